// Round 8
// baseline (191.876 us; speedup 1.0000x reference)
//
#include <hip/hip_runtime.h>
#include <math.h>

// CantorAttention: B=2, S=2048, DIM=512, H=8, HD=64, K=64
#define B_    2
#define S_    2048
#define DIM_  512
#define H_    8
#define HD_   64
#define K_    64
#define M_    (B_ * S_)          // 4096
#define NQKV_ (3 * DIM_)         // 1536

typedef __attribute__((ext_vector_type(8))) short          short8;    // mfma A/B frag (8 bf16)
typedef __attribute__((ext_vector_type(8))) unsigned short ushort8v;  // 16B move
typedef __attribute__((ext_vector_type(4))) float          float4v;   // mfma C/D frag

// ---- bf16 split helpers (RN-even) ------------------------------------------
__device__ __forceinline__ unsigned short f2bf_rn(float f) {
    unsigned int u = __float_as_uint(f);
    return (unsigned short)((u + 0x7FFFu + ((u >> 16) & 1u)) >> 16);
}
__device__ __forceinline__ float bf2f(unsigned short h) {
    return __uint_as_float((unsigned int)h << 16);
}
__device__ __forceinline__ float readlane_f(float v, int l) {
    return __int_as_float(__builtin_amdgcn_readlane(__float_as_int(v), l));
}

// async 16B global -> LDS (lane l lands at ldsbase + l*16)
__device__ __forceinline__ void load_lds16(const unsigned short* g, unsigned short* l) {
    __builtin_amdgcn_global_load_lds(
        (const __attribute__((address_space(1))) void*)g,
        (__attribute__((address_space(3))) void*)l, 16, 0, 0);
}

// ---------------------------------------------------------------------------
// prep_x: elementwise split fp32 -> (hi, lo) bf16 arrays. 8 elems/thread.
// ---------------------------------------------------------------------------
__global__ __launch_bounds__(256) void prep_x(const float* __restrict__ X,
                                              unsigned short* __restrict__ Hi,
                                              unsigned short* __restrict__ Lo)
{
    size_t i = ((size_t)blockIdx.x * 256 + threadIdx.x) * 8;
    float4 a = *(const float4*)&X[i];
    float4 b = *(const float4*)&X[i + 4];
    float f[8] = {a.x, a.y, a.z, a.w, b.x, b.y, b.z, b.w};
    ushort8v h, l;
    #pragma unroll
    for (int j = 0; j < 8; ++j) {
        unsigned short hh = f2bf_rn(f[j]);
        h[j] = hh;
        l[j] = f2bf_rn(f[j] - bf2f(hh));
    }
    *(ushort8v*)&Hi[i] = h;
    *(ushort8v*)&Lo[i] = l;
}

// ---------------------------------------------------------------------------
// prep_w: transpose + split W[Kd][N] fp32 -> Whi/Wlo [N][Kd] bf16.
// ---------------------------------------------------------------------------
__global__ __launch_bounds__(256) void prep_w(const float* __restrict__ W,
                                              unsigned short* __restrict__ Whi,
                                              unsigned short* __restrict__ Wlo,
                                              int Kd, int N)
{
    __shared__ float tile[32][33];
    const int k0 = blockIdx.y * 32, n0 = blockIdx.x * 32;
    const int c = threadIdx.x & 31, r8 = threadIdx.x >> 5;
    #pragma unroll
    for (int i = 0; i < 4; ++i) {
        int r = r8 + i * 8;
        tile[r][c] = W[(size_t)(k0 + r) * N + n0 + c];
    }
    __syncthreads();
    #pragma unroll
    for (int i = 0; i < 4; ++i) {
        int r = r8 + i * 8;                 // n offset
        float f = tile[c][r];               // = W[k0+c][n0+r]
        unsigned short hi = f2bf_rn(f);
        unsigned short lo = f2bf_rn(f - bf2f(hi));
        Whi[(size_t)(n0 + r) * Kd + k0 + c] = hi;
        Wlo[(size_t)(n0 + r) * Kd + k0 + c] = lo;
    }
}

// ---------------------------------------------------------------------------
// Split-bf16 MFMA GEMM (3 MFMAs: hi*hi + lo*hi + hi*lo).
// global_load_lds width=16 staging into unpadded [row][32] LDS. BK=32.
//   mode 0: row-major C.  mode 1: qkv scatter into Q/K/V [B,H,S,HD].
// ---------------------------------------------------------------------------
template<int BM, int BN, int WM, int WN>
__global__ __launch_bounds__(256) void gemm_mfma(
    const unsigned short* __restrict__ Ahi, const unsigned short* __restrict__ Alo,
    const unsigned short* __restrict__ Whi, const unsigned short* __restrict__ Wlo,
    const float* __restrict__ bias, float* __restrict__ C,
    float* __restrict__ Qo, float* __restrict__ Ko, float* __restrict__ Vo,
    int N, int Kd, int mode)
{
    constexpr int TM = WM / 16, TN = WN / 16;
    constexpr int WAVES_N = BN / WN;
    __shared__ unsigned short Ah[BM][32], Al[BM][32];
    __shared__ unsigned short Bh[BN][32], Bl[BN][32];

    const int t = threadIdx.x, lane = t & 63, wave = t >> 6;
    const int wm = (wave / WAVES_N) * WM, wn = (wave % WAVES_N) * WN;
    const int m0 = blockIdx.y * BM, n0 = blockIdx.x * BN;
    const int l15 = lane & 15, l4 = lane >> 4;

    const int srow = lane >> 2;          // 0..15
    const int scol = (lane & 3) * 8;     // 0,8,16,24

    float4v acc[TM][TN];
    #pragma unroll
    for (int i = 0; i < TM; ++i)
        #pragma unroll
        for (int j = 0; j < TN; ++j)
            #pragma unroll
            for (int r = 0; r < 4; ++r) acc[i][j][r] = 0.f;

    for (int k0 = 0; k0 < Kd; k0 += 32) {
        #pragma unroll
        for (int c = wave; c < BM / 16; c += 4) {
            size_t g = (size_t)(m0 + c * 16 + srow) * Kd + k0 + scol;
            load_lds16(&Ahi[g], &Ah[c * 16][0]);
            load_lds16(&Alo[g], &Al[c * 16][0]);
        }
        #pragma unroll
        for (int c = wave; c < BN / 16; c += 4) {
            size_t g = (size_t)(n0 + c * 16 + srow) * Kd + k0 + scol;
            load_lds16(&Whi[g], &Bh[c * 16][0]);
            load_lds16(&Wlo[g], &Bl[c * 16][0]);
        }
        __syncthreads();

        short8 fa_h[TM], fa_l[TM], fb_h[TN], fb_l[TN];
        #pragma unroll
        for (int im = 0; im < TM; ++im) {
            fa_h[im] = *(const short8*)&Ah[wm + im * 16 + l15][l4 * 8];
            fa_l[im] = *(const short8*)&Al[wm + im * 16 + l15][l4 * 8];
        }
        #pragma unroll
        for (int in = 0; in < TN; ++in) {
            fb_h[in] = *(const short8*)&Bh[wn + in * 16 + l15][l4 * 8];
            fb_l[in] = *(const short8*)&Bl[wn + in * 16 + l15][l4 * 8];
        }
        #pragma unroll
        for (int im = 0; im < TM; ++im)
            #pragma unroll
            for (int in = 0; in < TN; ++in) {
                acc[im][in] = __builtin_amdgcn_mfma_f32_16x16x32_bf16(fa_h[im], fb_h[in], acc[im][in], 0, 0, 0);
                acc[im][in] = __builtin_amdgcn_mfma_f32_16x16x32_bf16(fa_l[im], fb_h[in], acc[im][in], 0, 0, 0);
                acc[im][in] = __builtin_amdgcn_mfma_f32_16x16x32_bf16(fa_h[im], fb_l[in], acc[im][in], 0, 0, 0);
            }
        __syncthreads();
    }

    if (mode == 0) {
        #pragma unroll
        for (int in = 0; in < TN; ++in) {
            int n = n0 + wn + in * 16 + l15;
            float bv = bias[n];
            #pragma unroll
            for (int im = 0; im < TM; ++im) {
                int mb = m0 + wm + im * 16 + l4 * 4;
                #pragma unroll
                for (int r = 0; r < 4; ++r)
                    C[(size_t)(mb + r) * N + n] = acc[im][in][r] + bv;
            }
        }
    } else {
        #pragma unroll
        for (int in = 0; in < TN; ++in) {
            int n = n0 + wn + in * 16 + l15;
            int which = n >> 9, h = (n >> 6) & 7, d = n & 63;
            float* dst = (which == 0) ? Qo : (which == 1 ? Ko : Vo);
            float bv = bias[n];
            #pragma unroll
            for (int im = 0; im < TM; ++im) {
                int mb = m0 + wm + im * 16 + l4 * 4;
                #pragma unroll
                for (int r = 0; r < 4; ++r) {
                    int m = mb + r, b = m >> 11, s = m & 2047;
                    dst[(((size_t)b * H_ + h) * S_ + s) * HD_ + d] = acc[im][in][r] + bv;
                }
            }
        }
    }
}

// ---------------------------------------------------------------------------
// prep_groups: queries with identical Cantor coord share IDENTICAL route
// rows; routes[s][0] is a canonical group id. 16 blocks, each writing its OWN
// full metadata copy (stride 64 KB): block i -> XCD i&7; the attn consumers
// of copy i (bh == i, blockIdx = slot*16+i -> XCD i&7) sit on the SAME XCD,
// so no cross-XCD coherence is needed. Metadata lives in virgin d_out tail
// (never read by any kernel before the producer writes it).
// Copy layout (bytes): items int4[384] @0 ; order int[2048] @8192 ; nitems @16384.
// ---------------------------------------------------------------------------
__global__ __launch_bounds__(256) void prep_groups(
    const int* __restrict__ routes, char* __restrict__ meta)
{
    __shared__ int cnt[2048];
    __shared__ int offs[2048];
    __shared__ int tsum[256];
    const int t = threadIdx.x;

    char* my = meta + (size_t)blockIdx.x * 65536u;
    int4* items  = (int4*)my;
    int*  order  = (int*)(my + 8192);
    int*  nitems = (int*)(my + 16384);

    for (int i = t; i < 2048; i += 256) cnt[i] = 0;
    __syncthreads();
    for (int s = t; s < 2048; s += 256)
        atomicAdd(&cnt[routes[s * K_]], 1);
    __syncthreads();

    // exclusive scan of cnt -> offs
    int base = 0;
    #pragma unroll
    for (int i = 0; i < 8; ++i) base += cnt[t * 8 + i];
    tsum[t] = base;
    __syncthreads();
    for (int off = 1; off < 256; off <<= 1) {
        int v = (t >= off) ? tsum[t - off] : 0;
        __syncthreads();
        tsum[t] += v;
        __syncthreads();
    }
    {
        int run = tsum[t] - base;
        #pragma unroll
        for (int i = 0; i < 8; ++i) { offs[t * 8 + i] = run; run += cnt[t * 8 + i]; }
    }
    __syncthreads();

    // chunk items: nch = ceil(cnt/16) per group; scan chunk counts
    int cbase = 0;
    int nch[8];
    #pragma unroll
    for (int i = 0; i < 8; ++i) { nch[i] = (cnt[t * 8 + i] + 15) >> 4; cbase += nch[i]; }
    tsum[t] = cbase;
    __syncthreads();
    for (int off = 1; off < 256; off <<= 1) {
        int v = (t >= off) ? tsum[t - off] : 0;
        __syncthreads();
        tsum[t] += v;
        __syncthreads();
    }
    int cpos = tsum[t] - cbase;
    #pragma unroll
    for (int i = 0; i < 8; ++i) {
        int g = t * 8 + i;
        for (int c = 0; c < nch[i]; ++c) {
            int m = cnt[g] - c * 16; if (m > 16) m = 16;
            items[cpos++] = make_int4(g, offs[g] + c * 16, m, 0);
        }
    }
    if (t == 255) nitems[0] = tsum[255];
    __syncthreads();

    // fill member lists (reuse cnt as per-group fill counters)
    for (int i = t; i < 2048; i += 256) cnt[i] = 0;
    __syncthreads();
    for (int s = t; s < 2048; s += 256) {
        int g = routes[s * K_];
        int slot = atomicAdd(&cnt[g], 1);
        order[offs[g] + slot] = s;
    }
}

// ---------------------------------------------------------------------------
// Group-shared attention: one block per (slot, bh); reads its bh's OWN
// metadata copy (same-XCD producer). Gathers the group's 64 K rows (LDS,
// transposed [d][j], stride 64) and 64 V rows (row-major, stride 65) ONCE,
// then processes <=16 member queries (4 per wave). Grid 2048.
// ---------------------------------------------------------------------------
__global__ __launch_bounds__(256) void attn_group(
    const float* __restrict__ Q, const float* __restrict__ Kp,
    const float* __restrict__ V, const int* __restrict__ routes,
    const char* __restrict__ meta,
    unsigned short* __restrict__ Ohi, unsigned short* __restrict__ Olo)
{
    __shared__ float Kt[64 * 64];   // [d][j]
    __shared__ float Vr[64 * 65];   // [j][d], stride 65

    const int t = threadIdx.x, lane = t & 63, wave = t >> 6;
    const int bh = blockIdx.x & 15;
    const int b = bh >> 3, h = bh & 7;

    const char* my = meta + (size_t)bh * 65536u;
    const int4* items = (const int4*)my;
    const int*  order = (const int*)(my + 8192);
    const int   nit   = *(const int*)(my + 16384);

    for (int ii = blockIdx.x >> 4; ii < nit; ii += 128) {
        int4 itm = items[ii];
        const int g = itm.x, beg = itm.y, m = itm.z;

        // --- gather: waves 0,1 -> K ; waves 2,3 -> V. thread = (key j, half)
        {
            const int j = lane, half = wave & 1;
            const int rj = routes[g * K_ + j];
            if (wave < 2) {
                const float* src = Kp + ((size_t)bh * S_ + rj) * HD_ + half * 32;
                #pragma unroll
                for (int i = 0; i < 8; ++i) {
                    float4 kv = *(const float4*)(src + i * 4);
                    Kt[(half * 32 + i * 4 + 0) * 64 + j] = kv.x;
                    Kt[(half * 32 + i * 4 + 1) * 64 + j] = kv.y;
                    Kt[(half * 32 + i * 4 + 2) * 64 + j] = kv.z;
                    Kt[(half * 32 + i * 4 + 3) * 64 + j] = kv.w;
                }
            } else {
                const float* src = V + ((size_t)bh * S_ + rj) * HD_ + half * 32;
                #pragma unroll
                for (int i = 0; i < 8; ++i) {
                    float4 vv = *(const float4*)(src + i * 4);
                    Vr[j * 65 + half * 32 + i * 4 + 0] = vv.x;
                    Vr[j * 65 + half * 32 + i * 4 + 1] = vv.y;
                    Vr[j * 65 + half * 32 + i * 4 + 2] = vv.z;
                    Vr[j * 65 + half * 32 + i * 4 + 3] = vv.w;
                }
            }
        }

        // --- q vectors for this wave's 4 queries (lane = d)
        int   s_q[4], act[4];
        float qr[4];
        #pragma unroll
        for (int qi = 0; qi < 4; ++qi) {
            int idx = wave * 4 + qi;
            act[qi] = idx < m;
            int sA = order[beg + (act[qi] ? idx : 0)];
            s_q[qi] = sA;
            qr[qi] = Q[((size_t)bh * S_ + sA) * HD_ + lane];
        }
        __syncthreads();

        // --- phase 1: scores (lane = key j)
        float sc0 = 0.f, sc1 = 0.f, sc2 = 0.f, sc3 = 0.f;
        #pragma unroll
        for (int d = 0; d < 64; ++d) {
            float kv = Kt[d * 64 + lane];
            sc0 += readlane_f(qr[0], d) * kv;
            sc1 += readlane_f(qr[1], d) * kv;
            sc2 += readlane_f(qr[2], d) * kv;
            sc3 += readlane_f(qr[3], d) * kv;
        }
        sc0 *= 0.125f; sc1 *= 0.125f; sc2 *= 0.125f; sc3 *= 0.125f;

        // --- softmax (per query, 64-lane shuffle)
        float m0 = sc0, m1 = sc1, m2 = sc2, m3 = sc3;
        #pragma unroll
        for (int off = 32; off >= 1; off >>= 1) {
            m0 = fmaxf(m0, __shfl_xor(m0, off));
            m1 = fmaxf(m1, __shfl_xor(m1, off));
            m2 = fmaxf(m2, __shfl_xor(m2, off));
            m3 = fmaxf(m3, __shfl_xor(m3, off));
        }
        float e0 = __expf(sc0 - m0), e1 = __expf(sc1 - m1);
        float e2 = __expf(sc2 - m2), e3 = __expf(sc3 - m3);
        float u0 = e0, u1 = e1, u2 = e2, u3 = e3;
        #pragma unroll
        for (int off = 32; off >= 1; off >>= 1) {
            u0 += __shfl_xor(u0, off);
            u1 += __shfl_xor(u1, off);
            u2 += __shfl_xor(u2, off);
            u3 += __shfl_xor(u3, off);
        }
        const float w0 = e0 / u0, w1 = e1 / u1, w2 = e2 / u2, w3 = e3 / u3;

        // --- phase 2: out[qi][d=lane] = sum_j w[j] * V[j][d]
        float o0 = 0.f, o1 = 0.f, o2 = 0.f, o3 = 0.f;
        #pragma unroll
        for (int j = 0; j < 64; ++j) {
            float vv = Vr[j * 65 + lane];
            o0 += readlane_f(w0, j) * vv;
            o1 += readlane_f(w1, j) * vv;
            o2 += readlane_f(w2, j) * vv;
            o3 += readlane_f(w3, j) * vv;
        }

        float oq[4] = {o0, o1, o2, o3};
        #pragma unroll
        for (int qi = 0; qi < 4; ++qi) {
            if (act[qi]) {
                unsigned short hi = f2bf_rn(oq[qi]);
                unsigned short lo = f2bf_rn(oq[qi] - bf2f(hi));
                size_t oi = ((size_t)b * S_ + s_q[qi]) * DIM_ + h * HD_ + lane;
                Ohi[oi] = hi;
                Olo[oi] = lo;
            }
        }
        __syncthreads();   // protect LDS before next item's gather
    }
}

// ---------------------------------------------------------------------------
// ws layout (bytes):
//   0    Q 8MB | 8M K 8MB | 16M V 8MB | 24M x_hi/attn_hi 4MB | 28M x_lo/attn_lo 4MB
//   32M  Wqkv_hi 1.5M | +1.5M Wqkv_lo | +3M Wout_hi 0.5M | +3.5M Wout_lo
// Metadata: last 1 MB of d_out (16 copies x 64 KB) — virgin region, written
// by prep_groups each launch, consumed by attn_group (same-XCD pairs),
// overwritten by the final out-proj GEMM afterwards.
// ---------------------------------------------------------------------------
extern "C" void kernel_launch(void* const* d_in, const int* in_sizes, int n_in,
                              void* d_out, int out_size, void* d_ws, size_t ws_size,
                              hipStream_t stream)
{
    const float* x      = (const float*)d_in[0];
    const float* Wqkv   = (const float*)d_in[1];
    const float* bqkv   = (const float*)d_in[2];
    const float* Wout   = (const float*)d_in[3];
    const float* bout   = (const float*)d_in[4];
    const int*   routes = (const int*)d_in[5];
    float* out = (float*)d_out;

    char* w = (char*)d_ws;
    float* Q  = (float*)(w);
    float* Kp = (float*)(w + (8u << 20));
    float* V  = (float*)(w + (16u << 20));
    unsigned short* xh  = (unsigned short*)(w + (24u << 20));
    unsigned short* xl  = (unsigned short*)(w + (28u << 20));
    unsigned short* ah  = xh;   // aliased: free after qkv gemm
    unsigned short* al  = xl;
    unsigned short* wqh = (unsigned short*)(w + (32u << 20));
    unsigned short* wql = (unsigned short*)(w + (32u << 20) + 1572864u);
    unsigned short* woh = (unsigned short*)(w + (32u << 20) + 3145728u);
    unsigned short* wol = (unsigned short*)(w + (32u << 20) + 3670016u);
    // metadata in the last 1 MB of d_out (8 MB total): 16 copies x 64 KB
    char* meta = (char*)d_out + (8u << 20) - (1u << 20);

    dim3 blk(256);

    // metadata first: depends only on routes; d_out tail is virgin here
    prep_groups<<<dim3(16), blk, 0, stream>>>(routes, meta);

    prep_x<<<dim3((M_ * DIM_) / (256 * 8)), blk, 0, stream>>>(x, xh, xl);
    prep_w<<<dim3(NQKV_ / 32, DIM_ / 32), blk, 0, stream>>>(Wqkv, wqh, wql, DIM_, NQKV_);
    prep_w<<<dim3(DIM_ / 32, DIM_ / 32), blk, 0, stream>>>(Wout, woh, wol, DIM_, DIM_);

    // qkv: M=4096, N=1536, K=512 -> 512 blocks
    gemm_mfma<128, 96, 64, 48><<<dim3(NQKV_ / 96, M_ / 128), blk, 0, stream>>>(
        xh, xl, wqh, wql, bqkv, nullptr, Q, Kp, V, NQKV_, DIM_, 1);

    // grouped attention: 128 item-slots x 16 bh
    attn_group<<<dim3(2048), blk, 0, stream>>>(Q, Kp, V, routes, meta, ah, al);

    // out-proj: M=4096, N=512, K=512 -> 512 blocks (overwrites meta region too)
    gemm_mfma<64, 64, 32, 32><<<dim3(DIM_ / 64, M_ / 64), blk, 0, stream>>>(
        ah, al, woh, wol, bout, out, nullptr, nullptr, nullptr, DIM_, DIM_, 0);
}

// Round 9
// 165.524 us; speedup vs baseline: 1.1592x; 1.1592x over previous
//
#include <hip/hip_runtime.h>
#include <math.h>

// CantorAttention: B=2, S=2048, DIM=512, H=8, HD=64, K=64
#define B_    2
#define S_    2048
#define DIM_  512
#define H_    8
#define HD_   64
#define K_    64
#define M_    (B_ * S_)          // 4096
#define NQKV_ (3 * DIM_)         // 1536

typedef __attribute__((ext_vector_type(8))) short          short8;    // mfma A/B frag (8 bf16)
typedef __attribute__((ext_vector_type(8))) unsigned short ushort8v;  // 16B move
typedef __attribute__((ext_vector_type(4))) unsigned short ushort4v;  // 8B move
typedef __attribute__((ext_vector_type(4))) float          float4v;   // mfma C/D frag

// ---- bf16 split helpers (RN-even) ------------------------------------------
__device__ __forceinline__ unsigned short f2bf_rn(float f) {
    unsigned int u = __float_as_uint(f);
    return (unsigned short)((u + 0x7FFFu + ((u >> 16) & 1u)) >> 16);
}
__device__ __forceinline__ float bf2f(unsigned short h) {
    return __uint_as_float((unsigned int)h << 16);
}

// async 16B global -> LDS (lane l lands at ldsbase + l*16)
__device__ __forceinline__ void load_lds16(const unsigned short* g, unsigned short* l) {
    __builtin_amdgcn_global_load_lds(
        (const __attribute__((address_space(1))) void*)g,
        (__attribute__((address_space(3))) void*)l, 16, 0, 0);
}

// ---------------------------------------------------------------------------
// prep_x: elementwise split fp32 -> (hi, lo) bf16 arrays. 8 elems/thread.
// ---------------------------------------------------------------------------
__global__ __launch_bounds__(256) void prep_x(const float* __restrict__ X,
                                              unsigned short* __restrict__ Hi,
                                              unsigned short* __restrict__ Lo)
{
    size_t i = ((size_t)blockIdx.x * 256 + threadIdx.x) * 8;
    float4 a = *(const float4*)&X[i];
    float4 b = *(const float4*)&X[i + 4];
    float f[8] = {a.x, a.y, a.z, a.w, b.x, b.y, b.z, b.w};
    ushort8v h, l;
    #pragma unroll
    for (int j = 0; j < 8; ++j) {
        unsigned short hh = f2bf_rn(f[j]);
        h[j] = hh;
        l[j] = f2bf_rn(f[j] - bf2f(hh));
    }
    *(ushort8v*)&Hi[i] = h;
    *(ushort8v*)&Lo[i] = l;
}

// ---------------------------------------------------------------------------
// prep_w: transpose + split W[Kd][N] fp32 -> Whi/Wlo [N][Kd] bf16.
// ---------------------------------------------------------------------------
__global__ __launch_bounds__(256) void prep_w(const float* __restrict__ W,
                                              unsigned short* __restrict__ Whi,
                                              unsigned short* __restrict__ Wlo,
                                              int Kd, int N)
{
    __shared__ float tile[32][33];
    const int k0 = blockIdx.y * 32, n0 = blockIdx.x * 32;
    const int c = threadIdx.x & 31, r8 = threadIdx.x >> 5;
    #pragma unroll
    for (int i = 0; i < 4; ++i) {
        int r = r8 + i * 8;
        tile[r][c] = W[(size_t)(k0 + r) * N + n0 + c];
    }
    __syncthreads();
    #pragma unroll
    for (int i = 0; i < 4; ++i) {
        int r = r8 + i * 8;                 // n offset
        float f = tile[c][r];               // = W[k0+c][n0+r]
        unsigned short hi = f2bf_rn(f);
        unsigned short lo = f2bf_rn(f - bf2f(hi));
        Whi[(size_t)(n0 + r) * Kd + k0 + c] = hi;
        Wlo[(size_t)(n0 + r) * Kd + k0 + c] = lo;
    }
}

// ---------------------------------------------------------------------------
// Split-bf16 MFMA GEMM (3 MFMAs: hi*hi + lo*hi + hi*lo).
// DOUBLE-BUFFERED global_load_lds staging: the prefetch for k-step i+1 is
// issued BEFORE the compute of step i, so the barrier's vmcnt(0) drain
// overlaps with a full compute phase (addresses the m97 barrier-drain stall;
// one barrier per k-step instead of two).
//   mode 0: row-major C.  mode 1: qkv scatter into Q/K/V [B,H,S,HD].
// ---------------------------------------------------------------------------
template<int BM, int BN, int WM, int WN>
__global__ __launch_bounds__(256) void gemm_mfma(
    const unsigned short* __restrict__ Ahi, const unsigned short* __restrict__ Alo,
    const unsigned short* __restrict__ Whi, const unsigned short* __restrict__ Wlo,
    const float* __restrict__ bias, float* __restrict__ C,
    float* __restrict__ Qo, float* __restrict__ Ko, float* __restrict__ Vo,
    int N, int Kd, int mode)
{
    constexpr int TM = WM / 16, TN = WN / 16;
    constexpr int WAVES_N = BN / WN;
    __shared__ unsigned short Ah[2][BM][32], Al[2][BM][32];
    __shared__ unsigned short Bh[2][BN][32], Bl[2][BN][32];

    const int t = threadIdx.x, lane = t & 63, wave = t >> 6;
    const int wm = (wave / WAVES_N) * WM, wn = (wave % WAVES_N) * WN;
    const int m0 = blockIdx.y * BM, n0 = blockIdx.x * BN;
    const int l15 = lane & 15, l4 = lane >> 4;

    // staging: 1 KB per wave-issue = 16 rows x 64 B; lane l covers row
    // base+(l>>2), 16B k-chunk (l&3)*8 -> LDS off = l*16.
    const int srow = lane >> 2;          // 0..15
    const int scol = (lane & 3) * 8;     // 0,8,16,24

    float4v acc[TM][TN];
    #pragma unroll
    for (int i = 0; i < TM; ++i)
        #pragma unroll
        for (int j = 0; j < TN; ++j)
            #pragma unroll
            for (int r = 0; r < 4; ++r) acc[i][j][r] = 0.f;

    const int NK = Kd / 32;

    // prologue: stage k-step 0 into buffer 0
    #pragma unroll
    for (int c = wave; c < BM / 16; c += 4) {
        size_t g = (size_t)(m0 + c * 16 + srow) * Kd + scol;
        load_lds16(&Ahi[g], &Ah[0][c * 16][0]);
        load_lds16(&Alo[g], &Al[0][c * 16][0]);
    }
    #pragma unroll
    for (int c = wave; c < BN / 16; c += 4) {
        size_t g = (size_t)(n0 + c * 16 + srow) * Kd + scol;
        load_lds16(&Whi[g], &Bh[0][c * 16][0]);
        load_lds16(&Wlo[g], &Bl[0][c * 16][0]);
    }
    __syncthreads();

    for (int ks = 0; ks < NK; ++ks) {
        const int cur = ks & 1, nxt = cur ^ 1;

        // prefetch next k-step into the other buffer (async, ahead of compute)
        if (ks + 1 < NK) {
            const int k1 = (ks + 1) * 32;
            #pragma unroll
            for (int c = wave; c < BM / 16; c += 4) {
                size_t g = (size_t)(m0 + c * 16 + srow) * Kd + k1 + scol;
                load_lds16(&Ahi[g], &Ah[nxt][c * 16][0]);
                load_lds16(&Alo[g], &Al[nxt][c * 16][0]);
            }
            #pragma unroll
            for (int c = wave; c < BN / 16; c += 4) {
                size_t g = (size_t)(n0 + c * 16 + srow) * Kd + k1 + scol;
                load_lds16(&Whi[g], &Bh[nxt][c * 16][0]);
                load_lds16(&Wlo[g], &Bl[nxt][c * 16][0]);
            }
        }

        // compute current buffer
        short8 fa_h[TM], fa_l[TM], fb_h[TN], fb_l[TN];
        #pragma unroll
        for (int im = 0; im < TM; ++im) {
            fa_h[im] = *(const short8*)&Ah[cur][wm + im * 16 + l15][l4 * 8];
            fa_l[im] = *(const short8*)&Al[cur][wm + im * 16 + l15][l4 * 8];
        }
        #pragma unroll
        for (int in = 0; in < TN; ++in) {
            fb_h[in] = *(const short8*)&Bh[cur][wn + in * 16 + l15][l4 * 8];
            fb_l[in] = *(const short8*)&Bl[cur][wn + in * 16 + l15][l4 * 8];
        }
        #pragma unroll
        for (int im = 0; im < TM; ++im)
            #pragma unroll
            for (int in = 0; in < TN; ++in) {
                acc[im][in] = __builtin_amdgcn_mfma_f32_16x16x32_bf16(fa_h[im], fb_h[in], acc[im][in], 0, 0, 0);
                acc[im][in] = __builtin_amdgcn_mfma_f32_16x16x32_bf16(fa_l[im], fb_h[in], acc[im][in], 0, 0, 0);
                acc[im][in] = __builtin_amdgcn_mfma_f32_16x16x32_bf16(fa_h[im], fb_l[in], acc[im][in], 0, 0, 0);
            }

        // one barrier per k-step: protects cur (read) before it's re-staged,
        // and completes the nxt prefetch (vmcnt drain overlapped with compute)
        __syncthreads();
    }

    // epilogue: D row = (lane>>4)*4 + reg, col = lane&15  [m89-verified layout]
    if (mode == 0) {
        #pragma unroll
        for (int in = 0; in < TN; ++in) {
            int n = n0 + wn + in * 16 + l15;
            float bv = bias[n];
            #pragma unroll
            for (int im = 0; im < TM; ++im) {
                int mb = m0 + wm + im * 16 + l4 * 4;
                #pragma unroll
                for (int r = 0; r < 4; ++r)
                    C[(size_t)(mb + r) * N + n] = acc[im][in][r] + bv;
            }
        }
    } else {
        #pragma unroll
        for (int in = 0; in < TN; ++in) {
            int n = n0 + wn + in * 16 + l15;
            int which = n >> 9, h = (n >> 6) & 7, d = n & 63;
            float* dst = (which == 0) ? Qo : (which == 1 ? Ko : Vo);
            float bv = bias[n];
            #pragma unroll
            for (int im = 0; im < TM; ++im) {
                int mb = m0 + wm + im * 16 + l4 * 4;
                #pragma unroll
                for (int r = 0; r < 4; ++r) {
                    int m = mb + r, b = m >> 11, s = m & 2047;
                    dst[(((size_t)b * H_ + h) * S_ + s) * HD_ + d] = acc[im][in][r] + bv;
                }
            }
        }
    }
}

// ---------------------------------------------------------------------------
// Gathered attention (R4-proven, 54.4 us): TWO queries per wave, interleaved
// independent chains, XCD-pinned by (b,h). 4096 blocks.
// ---------------------------------------------------------------------------
__global__ __launch_bounds__(256) void attn_kernel(
    const float* __restrict__ Q, const float* __restrict__ Kp,
    const float* __restrict__ V, const int* __restrict__ routes,
    unsigned short* __restrict__ Ohi, unsigned short* __restrict__ Olo)
{
    __shared__ float q_s[4][2][64];
    __shared__ float w_s[4][2][64];

    const int wv = threadIdx.x >> 6, lane = threadIdx.x & 63;

    const int blk  = blockIdx.x;
    const int xcd  = blk & 7;
    const int idx  = blk >> 3;            // [0, 512)
    const int half = idx >> 8;            // 0 or 1
    const int sblk = idx & 255;           // [0, 256)
    const int bh   = xcd | (half << 3);   // [0, 16)
    const int s0   = sblk * 8 + wv * 2;   // this wave: s0, s0+1
    const int b    = bh >> 3, h = bh & 7;

    q_s[wv][0][lane] = Q[((size_t)bh * S_ + s0) * HD_ + lane];
    q_s[wv][1][lane] = Q[((size_t)bh * S_ + s0 + 1) * HD_ + lane];
    const int r0 = routes[s0 * K_ + lane];
    const int r1 = routes[(s0 + 1) * K_ + lane];
    __syncthreads();

    // phase 1: scores, 4 lanes/key, both queries interleaved.
    const int p = lane & 3, jl = lane >> 2;
    float qv0[16], qv1[16];
    #pragma unroll
    for (int i = 0; i < 16; ++i) {
        qv0[i] = q_s[wv][0][p * 16 + i];
        qv1[i] = q_s[wv][1][p * 16 + i];
    }

    const float* kbase = Kp + (size_t)bh * S_ * HD_;
    #pragma unroll
    for (int pass = 0; pass < 4; ++pass) {
        int j = pass * 16 + jl;
        int rj0 = __shfl(r0, j);
        int rj1 = __shfl(r1, j);
        const float* kp0 = kbase + (size_t)rj0 * HD_ + p * 16;
        const float* kp1 = kbase + (size_t)rj1 * HD_ + p * 16;
        float pa = 0.f, pb = 0.f;
        #pragma unroll
        for (int i = 0; i < 16; i += 4) {
            float4 k0v = *(const float4*)(kp0 + i);
            float4 k1v = *(const float4*)(kp1 + i);
            pa += qv0[i] * k0v.x + qv0[i + 1] * k0v.y + qv0[i + 2] * k0v.z + qv0[i + 3] * k0v.w;
            pb += qv1[i] * k1v.x + qv1[i + 1] * k1v.y + qv1[i + 2] * k1v.z + qv1[i + 3] * k1v.w;
        }
        pa += __shfl_xor(pa, 1);  pb += __shfl_xor(pb, 1);
        pa += __shfl_xor(pa, 2);  pb += __shfl_xor(pb, 2);
        if (p == 0) { w_s[wv][0][j] = pa * 0.125f; w_s[wv][1][j] = pb * 0.125f; }
    }
    __syncthreads();

    // softmax (two independent shuffle chains)
    float sa = w_s[wv][0][lane], sb = w_s[wv][1][lane];
    float ma = sa, mb = sb;
    #pragma unroll
    for (int off = 32; off >= 1; off >>= 1) {
        ma = fmaxf(ma, __shfl_xor(ma, off));
        mb = fmaxf(mb, __shfl_xor(mb, off));
    }
    float ea = __expf(sa - ma), eb = __expf(sb - mb);
    float su_a = ea, su_b = eb;
    #pragma unroll
    for (int off = 32; off >= 1; off >>= 1) {
        su_a += __shfl_xor(su_a, off);
        su_b += __shfl_xor(su_b, off);
    }
    const float w0 = ea / su_a, w1 = eb / su_b;   // weight for key = lane

    // phase 2: 4 keys/iter per query; lane: key-group g, d-slice dsl.
    const int g = lane >> 4, dsl = (lane & 15) * 4;
    const float* vbase = V + (size_t)bh * S_ * HD_;
    float a0x = 0.f, a0y = 0.f, a0z = 0.f, a0w = 0.f;
    float a1x = 0.f, a1y = 0.f, a1z = 0.f, a1w = 0.f;
    #pragma unroll
    for (int i = 0; i < 16; ++i) {
        int key = i * 4 + g;
        float wj0 = __shfl(w0, key), wj1 = __shfl(w1, key);
        int   rj0 = __shfl(r0, key), rj1 = __shfl(r1, key);
        float4 v0 = *(const float4*)&vbase[(size_t)rj0 * HD_ + dsl];
        float4 v1 = *(const float4*)&vbase[(size_t)rj1 * HD_ + dsl];
        a0x += wj0 * v0.x; a0y += wj0 * v0.y; a0z += wj0 * v0.z; a0w += wj0 * v0.w;
        a1x += wj1 * v1.x; a1y += wj1 * v1.y; a1z += wj1 * v1.z; a1w += wj1 * v1.w;
    }
    #pragma unroll
    for (int off = 16; off <= 32; off <<= 1) {
        a0x += __shfl_xor(a0x, off); a0y += __shfl_xor(a0y, off);
        a0z += __shfl_xor(a0z, off); a0w += __shfl_xor(a0w, off);
        a1x += __shfl_xor(a1x, off); a1y += __shfl_xor(a1y, off);
        a1z += __shfl_xor(a1z, off); a1w += __shfl_xor(a1w, off);
    }

    if (g == 0) {
        float o0[4] = {a0x, a0y, a0z, a0w};
        float o1[4] = {a1x, a1y, a1z, a1w};
        ushort4v h0, l0, h1, l1;
        #pragma unroll
        for (int i = 0; i < 4; ++i) {
            unsigned short hh0 = f2bf_rn(o0[i]);
            h0[i] = hh0; l0[i] = f2bf_rn(o0[i] - bf2f(hh0));
            unsigned short hh1 = f2bf_rn(o1[i]);
            h1[i] = hh1; l1[i] = f2bf_rn(o1[i] - bf2f(hh1));
        }
        size_t oi0 = ((size_t)b * S_ + s0) * DIM_ + h * HD_ + dsl;
        size_t oi1 = oi0 + DIM_;
        *(ushort4v*)&Ohi[oi0] = h0;  *(ushort4v*)&Olo[oi0] = l0;
        *(ushort4v*)&Ohi[oi1] = h1;  *(ushort4v*)&Olo[oi1] = l1;
    }
}

// ---------------------------------------------------------------------------
// ws layout (bytes):
//   0    Q 8MB | 8M K 8MB | 16M V 8MB | 24M x_hi/attn_hi 4MB | 28M x_lo/attn_lo 4MB
//   32M  Wqkv_hi 1.5M | +1.5M Wqkv_lo | +3M Wout_hi 0.5M | +3.5M Wout_lo
// ---------------------------------------------------------------------------
extern "C" void kernel_launch(void* const* d_in, const int* in_sizes, int n_in,
                              void* d_out, int out_size, void* d_ws, size_t ws_size,
                              hipStream_t stream)
{
    const float* x      = (const float*)d_in[0];
    const float* Wqkv   = (const float*)d_in[1];
    const float* bqkv   = (const float*)d_in[2];
    const float* Wout   = (const float*)d_in[3];
    const float* bout   = (const float*)d_in[4];
    const int*   routes = (const int*)d_in[5];
    float* out = (float*)d_out;

    char* w = (char*)d_ws;
    float* Q  = (float*)(w);
    float* Kp = (float*)(w + (8u << 20));
    float* V  = (float*)(w + (16u << 20));
    unsigned short* xh  = (unsigned short*)(w + (24u << 20));
    unsigned short* xl  = (unsigned short*)(w + (28u << 20));
    unsigned short* ah  = xh;   // aliased: free after qkv gemm
    unsigned short* al  = xl;
    unsigned short* wqh = (unsigned short*)(w + (32u << 20));
    unsigned short* wql = (unsigned short*)(w + (32u << 20) + 1572864u);
    unsigned short* woh = (unsigned short*)(w + (32u << 20) + 3145728u);
    unsigned short* wol = (unsigned short*)(w + (32u << 20) + 3670016u);

    dim3 blk(256);

    prep_x<<<dim3((M_ * DIM_) / (256 * 8)), blk, 0, stream>>>(x, xh, xl);
    prep_w<<<dim3(NQKV_ / 32, DIM_ / 32), blk, 0, stream>>>(Wqkv, wqh, wql, DIM_, NQKV_);
    prep_w<<<dim3(DIM_ / 32, DIM_ / 32), blk, 0, stream>>>(Wout, woh, wol, DIM_, DIM_);

    // qkv: M=4096, N=1536, K=512 -> 16x32 = 512 blocks (2/CU)
    gemm_mfma<128, 96, 64, 48><<<dim3(NQKV_ / 96, M_ / 128), blk, 0, stream>>>(
        xh, xl, wqh, wql, bqkv, nullptr, Q, Kp, V, NQKV_, DIM_, 1);

    attn_kernel<<<dim3((B_ * H_ * S_) / 8), blk, 0, stream>>>(Q, Kp, V, routes, ah, al);

    // out-proj: M=4096, N=512, K=512 -> 8x64 = 512 blocks (2/CU)
    gemm_mfma<64, 64, 32, 32><<<dim3(DIM_ / 64, M_ / 64), blk, 0, stream>>>(
        ah, al, woh, wol, bout, out, nullptr, nullptr, nullptr, DIM_, DIM_, 0);
}

// Round 10
// 151.891 us; speedup vs baseline: 1.2632x; 1.0898x over previous
//
#include <hip/hip_runtime.h>
#include <math.h>

// CantorAttention: B=2, S=2048, DIM=512, H=8, HD=64, K=64
#define B_    2
#define S_    2048
#define DIM_  512
#define H_    8
#define HD_   64
#define K_    64
#define M_    (B_ * S_)          // 4096
#define NQKV_ (3 * DIM_)         // 1536

typedef __attribute__((ext_vector_type(8))) short          short8;    // mfma A/B frag (8 bf16)
typedef __attribute__((ext_vector_type(8))) unsigned short ushort8v;  // 16B move
typedef __attribute__((ext_vector_type(4))) unsigned short ushort4v;  // 8B move
typedef __attribute__((ext_vector_type(4))) float          float4v;   // mfma C/D frag

// ---- bf16 split helpers (RN-even) ------------------------------------------
__device__ __forceinline__ unsigned short f2bf_rn(float f) {
    unsigned int u = __float_as_uint(f);
    return (unsigned short)((u + 0x7FFFu + ((u >> 16) & 1u)) >> 16);
}
__device__ __forceinline__ float bf2f(unsigned short h) {
    return __uint_as_float((unsigned int)h << 16);
}

// async 16B global -> LDS (lane l lands at ldsbase + l*16)
__device__ __forceinline__ void load_lds16(const unsigned short* g, unsigned short* l) {
    __builtin_amdgcn_global_load_lds(
        (const __attribute__((address_space(1))) void*)g,
        (__attribute__((address_space(3))) void*)l, 16, 0, 0);
}

// ---------------------------------------------------------------------------
// prep_all: one kernel, block-range partitioned.
//   blocks [0,1024): split x fp32 -> xh/xl bf16 (8 elems/thread)
//   blocks [1024,1792): transpose+split Wqkv (48 x 16 tiles of 32x32)
//   blocks [1792,2048): transpose+split Wout  (16 x 16 tiles)
// ---------------------------------------------------------------------------
__global__ __launch_bounds__(256) void prep_all(
    const float* __restrict__ X,
    unsigned short* __restrict__ Xhi, unsigned short* __restrict__ Xlo,
    const float* __restrict__ Wq,
    unsigned short* __restrict__ Wqh, unsigned short* __restrict__ Wql,
    const float* __restrict__ Wo,
    unsigned short* __restrict__ Woh, unsigned short* __restrict__ Wol)
{
    __shared__ float tile[32][33];
    const int bid = blockIdx.x, t = threadIdx.x;

    if (bid < 1024) {
        size_t i = ((size_t)bid * 256 + t) * 8;
        float4 a = *(const float4*)&X[i];
        float4 b = *(const float4*)&X[i + 4];
        float f[8] = {a.x, a.y, a.z, a.w, b.x, b.y, b.z, b.w};
        ushort8v h, l;
        #pragma unroll
        for (int j = 0; j < 8; ++j) {
            unsigned short hh = f2bf_rn(f[j]);
            h[j] = hh;
            l[j] = f2bf_rn(f[j] - bf2f(hh));
        }
        *(ushort8v*)&Xhi[i] = h;
        *(ushort8v*)&Xlo[i] = l;
        return;
    }

    const float* W;
    unsigned short *Whi, *Wlo;
    int N, k0, n0;
    if (bid < 1792) {
        int idx = bid - 1024;                  // 768 blocks: 48 n-tiles x 16 k-tiles
        W = Wq; Whi = Wqh; Wlo = Wql; N = NQKV_;
        n0 = (idx % 48) * 32; k0 = (idx / 48) * 32;
    } else {
        int idx = bid - 1792;                  // 256 blocks: 16 x 16
        W = Wo; Whi = Woh; Wlo = Wol; N = DIM_;
        n0 = (idx % 16) * 32; k0 = (idx / 16) * 32;
    }
    const int c = t & 31, r8 = t >> 5;
    #pragma unroll
    for (int i = 0; i < 4; ++i) {
        int r = r8 + i * 8;
        tile[r][c] = W[(size_t)(k0 + r) * N + n0 + c];
    }
    __syncthreads();
    #pragma unroll
    for (int i = 0; i < 4; ++i) {
        int r = r8 + i * 8;                 // n offset
        float f = tile[c][r];               // = W[k0+c][n0+r]
        unsigned short hi = f2bf_rn(f);
        unsigned short lo = f2bf_rn(f - bf2f(hi));
        Whi[(size_t)(n0 + r) * 512 + k0 + c] = hi;   // Kd = 512 for both
        Wlo[(size_t)(n0 + r) * 512 + k0 + c] = lo;
    }
}

// ---------------------------------------------------------------------------
// Split-bf16 MFMA GEMM (3 MFMAs: hi*hi + lo*hi + hi*lo), double-buffered
// global_load_lds staging (prefetch issued a full compute phase ahead).
//   mode 0: row-major fp32 C.
//   mode 1: qkv scatter -> Q fp32 / K bf16 / V fp32, layout [B,H,S,HD].
// ---------------------------------------------------------------------------
template<int BM, int BN, int WM, int WN>
__global__ __launch_bounds__(256) void gemm_mfma(
    const unsigned short* __restrict__ Ahi, const unsigned short* __restrict__ Alo,
    const unsigned short* __restrict__ Whi, const unsigned short* __restrict__ Wlo,
    const float* __restrict__ bias, float* __restrict__ C,
    float* __restrict__ Qo, unsigned short* __restrict__ Kbo, float* __restrict__ Vo,
    int N, int Kd, int mode)
{
    constexpr int TM = WM / 16, TN = WN / 16;
    constexpr int WAVES_N = BN / WN;
    __shared__ unsigned short Ah[2][BM][32], Al[2][BM][32];
    __shared__ unsigned short Bh[2][BN][32], Bl[2][BN][32];

    const int t = threadIdx.x, lane = t & 63, wave = t >> 6;
    const int wm = (wave / WAVES_N) * WM, wn = (wave % WAVES_N) * WN;
    const int m0 = blockIdx.y * BM, n0 = blockIdx.x * BN;
    const int l15 = lane & 15, l4 = lane >> 4;

    const int srow = lane >> 2;          // 0..15
    const int scol = (lane & 3) * 8;     // 0,8,16,24

    float4v acc[TM][TN];
    #pragma unroll
    for (int i = 0; i < TM; ++i)
        #pragma unroll
        for (int j = 0; j < TN; ++j)
            #pragma unroll
            for (int r = 0; r < 4; ++r) acc[i][j][r] = 0.f;

    const int NK = Kd / 32;

    #pragma unroll
    for (int c = wave; c < BM / 16; c += 4) {
        size_t g = (size_t)(m0 + c * 16 + srow) * Kd + scol;
        load_lds16(&Ahi[g], &Ah[0][c * 16][0]);
        load_lds16(&Alo[g], &Al[0][c * 16][0]);
    }
    #pragma unroll
    for (int c = wave; c < BN / 16; c += 4) {
        size_t g = (size_t)(n0 + c * 16 + srow) * Kd + scol;
        load_lds16(&Whi[g], &Bh[0][c * 16][0]);
        load_lds16(&Wlo[g], &Bl[0][c * 16][0]);
    }
    __syncthreads();

    for (int ks = 0; ks < NK; ++ks) {
        const int cur = ks & 1, nxt = cur ^ 1;

        if (ks + 1 < NK) {
            const int k1 = (ks + 1) * 32;
            #pragma unroll
            for (int c = wave; c < BM / 16; c += 4) {
                size_t g = (size_t)(m0 + c * 16 + srow) * Kd + k1 + scol;
                load_lds16(&Ahi[g], &Ah[nxt][c * 16][0]);
                load_lds16(&Alo[g], &Al[nxt][c * 16][0]);
            }
            #pragma unroll
            for (int c = wave; c < BN / 16; c += 4) {
                size_t g = (size_t)(n0 + c * 16 + srow) * Kd + k1 + scol;
                load_lds16(&Whi[g], &Bh[nxt][c * 16][0]);
                load_lds16(&Wlo[g], &Bl[nxt][c * 16][0]);
            }
        }

        short8 fa_h[TM], fa_l[TM], fb_h[TN], fb_l[TN];
        #pragma unroll
        for (int im = 0; im < TM; ++im) {
            fa_h[im] = *(const short8*)&Ah[cur][wm + im * 16 + l15][l4 * 8];
            fa_l[im] = *(const short8*)&Al[cur][wm + im * 16 + l15][l4 * 8];
        }
        #pragma unroll
        for (int in = 0; in < TN; ++in) {
            fb_h[in] = *(const short8*)&Bh[cur][wn + in * 16 + l15][l4 * 8];
            fb_l[in] = *(const short8*)&Bl[cur][wn + in * 16 + l15][l4 * 8];
        }
        #pragma unroll
        for (int im = 0; im < TM; ++im)
            #pragma unroll
            for (int in = 0; in < TN; ++in) {
                acc[im][in] = __builtin_amdgcn_mfma_f32_16x16x32_bf16(fa_h[im], fb_h[in], acc[im][in], 0, 0, 0);
                acc[im][in] = __builtin_amdgcn_mfma_f32_16x16x32_bf16(fa_l[im], fb_h[in], acc[im][in], 0, 0, 0);
                acc[im][in] = __builtin_amdgcn_mfma_f32_16x16x32_bf16(fa_h[im], fb_l[in], acc[im][in], 0, 0, 0);
            }

        __syncthreads();
    }

    // epilogue: D row = (lane>>4)*4 + reg, col = lane&15  [m89-verified layout]
    if (mode == 0) {
        #pragma unroll
        for (int in = 0; in < TN; ++in) {
            int n = n0 + wn + in * 16 + l15;
            float bv = bias[n];
            #pragma unroll
            for (int im = 0; im < TM; ++im) {
                int mb = m0 + wm + im * 16 + l4 * 4;
                #pragma unroll
                for (int r = 0; r < 4; ++r)
                    C[(size_t)(mb + r) * N + n] = acc[im][in][r] + bv;
            }
        }
    } else {
        #pragma unroll
        for (int in = 0; in < TN; ++in) {
            int n = n0 + wn + in * 16 + l15;
            int which = n >> 9, h = (n >> 6) & 7, d = n & 63;
            float bv = bias[n];
            #pragma unroll
            for (int im = 0; im < TM; ++im) {
                int mb = m0 + wm + im * 16 + l4 * 4;
                #pragma unroll
                for (int r = 0; r < 4; ++r) {
                    int m = mb + r, b = m >> 11, s = m & 2047;
                    size_t idx = (((size_t)b * H_ + h) * S_ + s) * HD_ + d;
                    float val = acc[im][in][r] + bv;
                    if (which == 0)      Qo[idx]  = val;
                    else if (which == 2) Vo[idx]  = val;
                    else                 Kbo[idx] = f2bf_rn(val);
                }
            }
        }
    }
}

// ---------------------------------------------------------------------------
// Gathered attention: TWO queries per wave, XCD-pinned by (b,h). K is bf16
// (8 elems per 16B lane-load -> phase-1 load count halved vs fp32); Q and V
// remain fp32. 4096 blocks.
// ---------------------------------------------------------------------------
__global__ __launch_bounds__(256) void attn_kernel(
    const float* __restrict__ Q, const unsigned short* __restrict__ Kb,
    const float* __restrict__ V, const int* __restrict__ routes,
    unsigned short* __restrict__ Ohi, unsigned short* __restrict__ Olo)
{
    __shared__ float q_s[4][2][64];
    __shared__ float w_s[4][2][64];

    const int wv = threadIdx.x >> 6, lane = threadIdx.x & 63;

    const int blk  = blockIdx.x;
    const int xcd  = blk & 7;
    const int idx  = blk >> 3;            // [0, 512)
    const int half = idx >> 8;            // 0 or 1
    const int sblk = idx & 255;           // [0, 256)
    const int bh   = xcd | (half << 3);   // [0, 16)
    const int s0   = sblk * 8 + wv * 2;   // this wave: s0, s0+1
    const int b    = bh >> 3, h = bh & 7;

    q_s[wv][0][lane] = Q[((size_t)bh * S_ + s0) * HD_ + lane];
    q_s[wv][1][lane] = Q[((size_t)bh * S_ + s0 + 1) * HD_ + lane];
    const int r0 = routes[s0 * K_ + lane];
    const int r1 = routes[(s0 + 1) * K_ + lane];
    __syncthreads();

    // phase 1: scores. 8 lanes per key (8 bf16 = 16B per lane), 8 keys/pass.
    const int p = lane & 7, jl = lane >> 3;
    float qv0[8], qv1[8];
    #pragma unroll
    for (int i = 0; i < 8; ++i) {
        qv0[i] = q_s[wv][0][p * 8 + i];
        qv1[i] = q_s[wv][1][p * 8 + i];
    }

    const unsigned short* kbase = Kb + (size_t)bh * S_ * HD_;
    #pragma unroll
    for (int pass = 0; pass < 8; ++pass) {
        int j = pass * 8 + jl;
        int rj0 = __shfl(r0, j);
        int rj1 = __shfl(r1, j);
        ushort8v k0 = *(const ushort8v*)&kbase[(size_t)rj0 * HD_ + p * 8];
        ushort8v k1 = *(const ushort8v*)&kbase[(size_t)rj1 * HD_ + p * 8];
        float pa = 0.f, pb = 0.f;
        #pragma unroll
        for (int i = 0; i < 8; ++i) {
            pa += qv0[i] * bf2f(k0[i]);
            pb += qv1[i] * bf2f(k1[i]);
        }
        pa += __shfl_xor(pa, 1);  pb += __shfl_xor(pb, 1);
        pa += __shfl_xor(pa, 2);  pb += __shfl_xor(pb, 2);
        pa += __shfl_xor(pa, 4);  pb += __shfl_xor(pb, 4);
        if (p == 0) { w_s[wv][0][j] = pa * 0.125f; w_s[wv][1][j] = pb * 0.125f; }
    }
    __syncthreads();

    // softmax (two independent shuffle chains)
    float sa = w_s[wv][0][lane], sb = w_s[wv][1][lane];
    float ma = sa, mb = sb;
    #pragma unroll
    for (int off = 32; off >= 1; off >>= 1) {
        ma = fmaxf(ma, __shfl_xor(ma, off));
        mb = fmaxf(mb, __shfl_xor(mb, off));
    }
    float ea = __expf(sa - ma), eb = __expf(sb - mb);
    float su_a = ea, su_b = eb;
    #pragma unroll
    for (int off = 32; off >= 1; off >>= 1) {
        su_a += __shfl_xor(su_a, off);
        su_b += __shfl_xor(su_b, off);
    }
    const float w0 = ea / su_a, w1 = eb / su_b;   // weight for key = lane

    // phase 2: 4 keys/iter per query; lane: key-group g, d-slice dsl. V fp32.
    const int g = lane >> 4, dsl = (lane & 15) * 4;
    const float* vbase = V + (size_t)bh * S_ * HD_;
    float a0x = 0.f, a0y = 0.f, a0z = 0.f, a0w = 0.f;
    float a1x = 0.f, a1y = 0.f, a1z = 0.f, a1w = 0.f;
    #pragma unroll
    for (int i = 0; i < 16; ++i) {
        int key = i * 4 + g;
        float wj0 = __shfl(w0, key), wj1 = __shfl(w1, key);
        int   rj0 = __shfl(r0, key), rj1 = __shfl(r1, key);
        float4 v0 = *(const float4*)&vbase[(size_t)rj0 * HD_ + dsl];
        float4 v1 = *(const float4*)&vbase[(size_t)rj1 * HD_ + dsl];
        a0x += wj0 * v0.x; a0y += wj0 * v0.y; a0z += wj0 * v0.z; a0w += wj0 * v0.w;
        a1x += wj1 * v1.x; a1y += wj1 * v1.y; a1z += wj1 * v1.z; a1w += wj1 * v1.w;
    }
    #pragma unroll
    for (int off = 16; off <= 32; off <<= 1) {
        a0x += __shfl_xor(a0x, off); a0y += __shfl_xor(a0y, off);
        a0z += __shfl_xor(a0z, off); a0w += __shfl_xor(a0w, off);
        a1x += __shfl_xor(a1x, off); a1y += __shfl_xor(a1y, off);
        a1z += __shfl_xor(a1z, off); a1w += __shfl_xor(a1w, off);
    }

    if (g == 0) {
        float o0[4] = {a0x, a0y, a0z, a0w};
        float o1[4] = {a1x, a1y, a1z, a1w};
        ushort4v h0, l0, h1, l1;
        #pragma unroll
        for (int i = 0; i < 4; ++i) {
            unsigned short hh0 = f2bf_rn(o0[i]);
            h0[i] = hh0; l0[i] = f2bf_rn(o0[i] - bf2f(hh0));
            unsigned short hh1 = f2bf_rn(o1[i]);
            h1[i] = hh1; l1[i] = f2bf_rn(o1[i] - bf2f(hh1));
        }
        size_t oi0 = ((size_t)b * S_ + s0) * DIM_ + h * HD_ + dsl;
        size_t oi1 = oi0 + DIM_;
        *(ushort4v*)&Ohi[oi0] = h0;  *(ushort4v*)&Olo[oi0] = l0;
        *(ushort4v*)&Ohi[oi1] = h1;  *(ushort4v*)&Olo[oi1] = l1;
    }
}

// ---------------------------------------------------------------------------
// ws layout (bytes):
//   0    Q fp32 8MB | 8M K bf16 4MB | 16M V fp32 8MB
//   24M  x_hi/attn_hi 4MB | 28M x_lo/attn_lo 4MB
//   32M  Wqkv_hi 1.5M | +1.5M Wqkv_lo | +3M Wout_hi 0.5M | +3.5M Wout_lo
// ---------------------------------------------------------------------------
extern "C" void kernel_launch(void* const* d_in, const int* in_sizes, int n_in,
                              void* d_out, int out_size, void* d_ws, size_t ws_size,
                              hipStream_t stream)
{
    const float* x      = (const float*)d_in[0];
    const float* Wqkv   = (const float*)d_in[1];
    const float* bqkv   = (const float*)d_in[2];
    const float* Wout   = (const float*)d_in[3];
    const float* bout   = (const float*)d_in[4];
    const int*   routes = (const int*)d_in[5];
    float* out = (float*)d_out;

    char* w = (char*)d_ws;
    float*          Q  = (float*)(w);
    unsigned short* Kb = (unsigned short*)(w + (8u << 20));
    float*          V  = (float*)(w + (16u << 20));
    unsigned short* xh  = (unsigned short*)(w + (24u << 20));
    unsigned short* xl  = (unsigned short*)(w + (28u << 20));
    unsigned short* ah  = xh;   // aliased: free after qkv gemm
    unsigned short* al  = xl;
    unsigned short* wqh = (unsigned short*)(w + (32u << 20));
    unsigned short* wql = (unsigned short*)(w + (32u << 20) + 1572864u);
    unsigned short* woh = (unsigned short*)(w + (32u << 20) + 3145728u);
    unsigned short* wol = (unsigned short*)(w + (32u << 20) + 3670016u);

    dim3 blk(256);

    // fused prep: x-split (1024 blocks) + Wqkv t-split (768) + Wout t-split (256)
    prep_all<<<dim3(2048), blk, 0, stream>>>(x, xh, xl, Wqkv, wqh, wql, Wout, woh, wol);

    // qkv: M=4096, N=1536, K=512 -> 16x32 = 512 blocks (2/CU)
    gemm_mfma<128, 96, 64, 48><<<dim3(NQKV_ / 96, M_ / 128), blk, 0, stream>>>(
        xh, xl, wqh, wql, bqkv, nullptr, Q, Kb, V, NQKV_, DIM_, 1);

    attn_kernel<<<dim3((B_ * H_ * S_) / 8), blk, 0, stream>>>(Q, Kb, V, routes, ah, al);

    // out-proj: M=4096, N=512, K=512 -> 8x64 = 512 blocks (2/CU)
    gemm_mfma<64, 64, 32, 32><<<dim3(DIM_ / 64, M_ / 64), blk, 0, stream>>>(
        ah, al, woh, wol, bout, out, nullptr, nullptr, nullptr, DIM_, DIM_, 0);
}

// Round 11
// 148.605 us; speedup vs baseline: 1.2912x; 1.0221x over previous
//
#include <hip/hip_runtime.h>
#include <math.h>

// CantorAttention: B=2, S=2048, DIM=512, H=8, HD=64, K=64
#define B_    2
#define S_    2048
#define DIM_  512
#define H_    8
#define HD_   64
#define K_    64
#define M_    (B_ * S_)          // 4096
#define NQKV_ (3 * DIM_)         // 1536

typedef __attribute__((ext_vector_type(8))) _Float16       half8;     // mfma A/B frag (8 f16)
typedef __attribute__((ext_vector_type(8))) unsigned short ushort8v;  // 16B move
typedef __attribute__((ext_vector_type(4))) float          float4v;   // mfma C/D frag

// ---- fp16 helpers ----------------------------------------------------------
__device__ __forceinline__ unsigned short f2h(float f) {
    _Float16 h = (_Float16)f;
    unsigned short u; __builtin_memcpy(&u, &h, 2); return u;
}
__device__ __forceinline__ float h2f(unsigned short u) {
    _Float16 h; __builtin_memcpy(&h, &u, 2); return (float)h;
}

// async 16B global -> LDS (lane l lands at ldsbase + l*16)
__device__ __forceinline__ void load_lds16(const unsigned short* g, unsigned short* l) {
    __builtin_amdgcn_global_load_lds(
        (const __attribute__((address_space(1))) void*)g,
        (__attribute__((address_space(3))) void*)l, 16, 0, 0);
}

// ---------------------------------------------------------------------------
// prep_all: one kernel, block-range partitioned.
//   [0,1024): split x fp32 -> xh/xl fp16 (8 elems/thread)
//   [1024,1792): transpose Wqkv -> Wqh fp16 [N][Kd] (48 x 16 tiles of 32x32)
//   [1792,2048): transpose Wout -> Woh fp16 (16 x 16 tiles)
// fp16 2-term scheme: W-lo never needed (error |a*wl| ~ 2^-11 relative).
// ---------------------------------------------------------------------------
__global__ __launch_bounds__(256) void prep_all(
    const float* __restrict__ X,
    unsigned short* __restrict__ Xhi, unsigned short* __restrict__ Xlo,
    const float* __restrict__ Wq, unsigned short* __restrict__ Wqh,
    const float* __restrict__ Wo, unsigned short* __restrict__ Woh)
{
    __shared__ float tile[32][33];
    const int bid = blockIdx.x, t = threadIdx.x;

    if (bid < 1024) {
        size_t i = ((size_t)bid * 256 + t) * 8;
        float4 a = *(const float4*)&X[i];
        float4 b = *(const float4*)&X[i + 4];
        float f[8] = {a.x, a.y, a.z, a.w, b.x, b.y, b.z, b.w};
        ushort8v h, l;
        #pragma unroll
        for (int j = 0; j < 8; ++j) {
            unsigned short hh = f2h(f[j]);
            h[j] = hh;
            l[j] = f2h(f[j] - h2f(hh));
        }
        *(ushort8v*)&Xhi[i] = h;
        *(ushort8v*)&Xlo[i] = l;
        return;
    }

    const float* W;
    unsigned short* Whi;
    int N, k0, n0;
    if (bid < 1792) {
        int idx = bid - 1024;                  // 768 blocks: 48 n-tiles x 16 k-tiles
        W = Wq; Whi = Wqh; N = NQKV_;
        n0 = (idx % 48) * 32; k0 = (idx / 48) * 32;
    } else {
        int idx = bid - 1792;                  // 256 blocks: 16 x 16
        W = Wo; Whi = Woh; N = DIM_;
        n0 = (idx % 16) * 32; k0 = (idx / 16) * 32;
    }
    const int c = t & 31, r8 = t >> 5;
    #pragma unroll
    for (int i = 0; i < 4; ++i) {
        int r = r8 + i * 8;
        tile[r][c] = W[(size_t)(k0 + r) * N + n0 + c];
    }
    __syncthreads();
    #pragma unroll
    for (int i = 0; i < 4; ++i) {
        int r = r8 + i * 8;                 // n offset
        Whi[(size_t)(n0 + r) * 512 + k0 + c] = f2h(tile[c][r]);   // Kd = 512
    }
}

// ---------------------------------------------------------------------------
// Split-fp16 MFMA GEMM, 2 terms: C = (Ah + Al) * Wh  (error |A*Wl| ~ 2^-11).
// Double-buffered global_load_lds staging (prefetch a full compute phase
// ahead of the barrier).
//   mode 0: row-major fp32 C.
//   mode 1: qkv scatter -> Q fp32 / K fp16 / V fp16, layout [B,H,S,HD].
// ---------------------------------------------------------------------------
template<int BM, int BN, int WM, int WN>
__global__ __launch_bounds__(256) void gemm_mfma(
    const unsigned short* __restrict__ Ahi, const unsigned short* __restrict__ Alo,
    const unsigned short* __restrict__ Wh,
    const float* __restrict__ bias, float* __restrict__ C,
    float* __restrict__ Qo, unsigned short* __restrict__ Kho, unsigned short* __restrict__ Vho,
    int N, int Kd, int mode)
{
    constexpr int TM = WM / 16, TN = WN / 16;
    constexpr int WAVES_N = BN / WN;
    __shared__ unsigned short Ah[2][BM][32], Al[2][BM][32];
    __shared__ unsigned short Bh[2][BN][32];

    const int t = threadIdx.x, lane = t & 63, wave = t >> 6;
    const int wm = (wave / WAVES_N) * WM, wn = (wave % WAVES_N) * WN;
    const int m0 = blockIdx.y * BM, n0 = blockIdx.x * BN;
    const int l15 = lane & 15, l4 = lane >> 4;

    const int srow = lane >> 2;          // 0..15
    const int scol = (lane & 3) * 8;     // 0,8,16,24

    float4v acc[TM][TN];
    #pragma unroll
    for (int i = 0; i < TM; ++i)
        #pragma unroll
        for (int j = 0; j < TN; ++j)
            #pragma unroll
            for (int r = 0; r < 4; ++r) acc[i][j][r] = 0.f;

    const int NK = Kd / 32;

    #pragma unroll
    for (int c = wave; c < BM / 16; c += 4) {
        size_t g = (size_t)(m0 + c * 16 + srow) * Kd + scol;
        load_lds16(&Ahi[g], &Ah[0][c * 16][0]);
        load_lds16(&Alo[g], &Al[0][c * 16][0]);
    }
    #pragma unroll
    for (int c = wave; c < BN / 16; c += 4) {
        size_t g = (size_t)(n0 + c * 16 + srow) * Kd + scol;
        load_lds16(&Wh[g], &Bh[0][c * 16][0]);
    }
    __syncthreads();

    for (int ks = 0; ks < NK; ++ks) {
        const int cur = ks & 1, nxt = cur ^ 1;

        if (ks + 1 < NK) {
            const int k1 = (ks + 1) * 32;
            #pragma unroll
            for (int c = wave; c < BM / 16; c += 4) {
                size_t g = (size_t)(m0 + c * 16 + srow) * Kd + k1 + scol;
                load_lds16(&Ahi[g], &Ah[nxt][c * 16][0]);
                load_lds16(&Alo[g], &Al[nxt][c * 16][0]);
            }
            #pragma unroll
            for (int c = wave; c < BN / 16; c += 4) {
                size_t g = (size_t)(n0 + c * 16 + srow) * Kd + k1 + scol;
                load_lds16(&Wh[g], &Bh[nxt][c * 16][0]);
            }
        }

        half8 fa_h[TM], fa_l[TM], fb[TN];
        #pragma unroll
        for (int im = 0; im < TM; ++im) {
            fa_h[im] = *(const half8*)&Ah[cur][wm + im * 16 + l15][l4 * 8];
            fa_l[im] = *(const half8*)&Al[cur][wm + im * 16 + l15][l4 * 8];
        }
        #pragma unroll
        for (int in = 0; in < TN; ++in)
            fb[in] = *(const half8*)&Bh[cur][wn + in * 16 + l15][l4 * 8];
        #pragma unroll
        for (int im = 0; im < TM; ++im)
            #pragma unroll
            for (int in = 0; in < TN; ++in) {
                acc[im][in] = __builtin_amdgcn_mfma_f32_16x16x32_f16(fa_h[im], fb[in], acc[im][in], 0, 0, 0);
                acc[im][in] = __builtin_amdgcn_mfma_f32_16x16x32_f16(fa_l[im], fb[in], acc[im][in], 0, 0, 0);
            }

        __syncthreads();
    }

    // epilogue: D row = (lane>>4)*4 + reg, col = lane&15  [m89-verified layout]
    if (mode == 0) {
        #pragma unroll
        for (int in = 0; in < TN; ++in) {
            int n = n0 + wn + in * 16 + l15;
            float bv = bias[n];
            #pragma unroll
            for (int im = 0; im < TM; ++im) {
                int mb = m0 + wm + im * 16 + l4 * 4;
                #pragma unroll
                for (int r = 0; r < 4; ++r)
                    C[(size_t)(mb + r) * N + n] = acc[im][in][r] + bv;
            }
        }
    } else {
        #pragma unroll
        for (int in = 0; in < TN; ++in) {
            int n = n0 + wn + in * 16 + l15;
            int which = n >> 9, h = (n >> 6) & 7, d = n & 63;
            float bv = bias[n];
            #pragma unroll
            for (int im = 0; im < TM; ++im) {
                int mb = m0 + wm + im * 16 + l4 * 4;
                #pragma unroll
                for (int r = 0; r < 4; ++r) {
                    int m = mb + r, b = m >> 11, s = m & 2047;
                    size_t idx = (((size_t)b * H_ + h) * S_ + s) * HD_ + d;
                    float val = acc[im][in][r] + bv;
                    if (which == 0)      Qo[idx]  = val;
                    else if (which == 1) Kho[idx] = f2h(val);
                    else                 Vho[idx] = f2h(val);
                }
            }
        }
    }
}

// ---------------------------------------------------------------------------
// Gathered attention: TWO queries per wave, XCD-pinned by (b,h). K and V are
// fp16 (16B lane-loads cover 8 elems -> load count and line-touches halved).
// Phase 2: 8 key-groups x 8-d slices, cross-group shuffle reduce. Output
// written as fp16 hi/lo split for the out-projection GEMM. 4096 blocks.
// ---------------------------------------------------------------------------
__global__ __launch_bounds__(256) void attn_kernel(
    const float* __restrict__ Q, const unsigned short* __restrict__ Kh,
    const unsigned short* __restrict__ Vh, const int* __restrict__ routes,
    unsigned short* __restrict__ Ohi, unsigned short* __restrict__ Olo)
{
    __shared__ float q_s[4][2][64];
    __shared__ float w_s[4][2][64];

    const int wv = threadIdx.x >> 6, lane = threadIdx.x & 63;

    const int blk  = blockIdx.x;
    const int xcd  = blk & 7;
    const int idx  = blk >> 3;            // [0, 512)
    const int half = idx >> 8;            // 0 or 1
    const int sblk = idx & 255;           // [0, 256)
    const int bh   = xcd | (half << 3);   // [0, 16)
    const int s0   = sblk * 8 + wv * 2;   // this wave: s0, s0+1
    const int b    = bh >> 3, h = bh & 7;

    q_s[wv][0][lane] = Q[((size_t)bh * S_ + s0) * HD_ + lane];
    q_s[wv][1][lane] = Q[((size_t)bh * S_ + s0 + 1) * HD_ + lane];
    const int r0 = routes[s0 * K_ + lane];
    const int r1 = routes[(s0 + 1) * K_ + lane];
    __syncthreads();

    // phase 1: scores. 8 lanes per key (8 f16 = 16B per lane), 8 keys/pass.
    const int p = lane & 7, jl = lane >> 3;
    float qv0[8], qv1[8];
    #pragma unroll
    for (int i = 0; i < 8; ++i) {
        qv0[i] = q_s[wv][0][p * 8 + i];
        qv1[i] = q_s[wv][1][p * 8 + i];
    }

    const unsigned short* kbase = Kh + (size_t)bh * S_ * HD_;
    #pragma unroll
    for (int pass = 0; pass < 8; ++pass) {
        int j = pass * 8 + jl;
        int rj0 = __shfl(r0, j);
        int rj1 = __shfl(r1, j);
        ushort8v k0 = *(const ushort8v*)&kbase[(size_t)rj0 * HD_ + p * 8];
        ushort8v k1 = *(const ushort8v*)&kbase[(size_t)rj1 * HD_ + p * 8];
        float pa = 0.f, pb = 0.f;
        #pragma unroll
        for (int i = 0; i < 8; ++i) {
            pa += qv0[i] * h2f(k0[i]);
            pb += qv1[i] * h2f(k1[i]);
        }
        pa += __shfl_xor(pa, 1);  pb += __shfl_xor(pb, 1);
        pa += __shfl_xor(pa, 2);  pb += __shfl_xor(pb, 2);
        pa += __shfl_xor(pa, 4);  pb += __shfl_xor(pb, 4);
        if (p == 0) { w_s[wv][0][j] = pa * 0.125f; w_s[wv][1][j] = pb * 0.125f; }
    }
    __syncthreads();

    // softmax (two independent shuffle chains)
    float sa = w_s[wv][0][lane], sb = w_s[wv][1][lane];
    float ma = sa, mb = sb;
    #pragma unroll
    for (int off = 32; off >= 1; off >>= 1) {
        ma = fmaxf(ma, __shfl_xor(ma, off));
        mb = fmaxf(mb, __shfl_xor(mb, off));
    }
    float ea = __expf(sa - ma), eb = __expf(sb - mb);
    float su_a = ea, su_b = eb;
    #pragma unroll
    for (int off = 32; off >= 1; off >>= 1) {
        su_a += __shfl_xor(su_a, off);
        su_b += __shfl_xor(su_b, off);
    }
    const float w0 = ea / su_a, w1 = eb / su_b;   // weight for key = lane

    // phase 2: lane = (key-group kg = lane>>3, d-slice p8 = lane&7).
    // 8 iters, each lane loads 16B (8 f16) of one V row.
    const int kg = lane >> 3, p8 = lane & 7;
    const unsigned short* vbase = Vh + (size_t)bh * S_ * HD_;
    float ac0[8] = {0.f,0.f,0.f,0.f,0.f,0.f,0.f,0.f};
    float ac1[8] = {0.f,0.f,0.f,0.f,0.f,0.f,0.f,0.f};
    #pragma unroll
    for (int i = 0; i < 8; ++i) {
        int key = i * 8 + kg;
        float wj0 = __shfl(w0, key), wj1 = __shfl(w1, key);
        int   rj0 = __shfl(r0, key), rj1 = __shfl(r1, key);
        ushort8v v0 = *(const ushort8v*)&vbase[(size_t)rj0 * HD_ + p8 * 8];
        ushort8v v1 = *(const ushort8v*)&vbase[(size_t)rj1 * HD_ + p8 * 8];
        #pragma unroll
        for (int j = 0; j < 8; ++j) {
            ac0[j] += wj0 * h2f(v0[j]);
            ac1[j] += wj1 * h2f(v1[j]);
        }
    }
    // reduce across the 8 key-groups (lanes with same p8, kg varying)
    #pragma unroll
    for (int off = 8; off <= 32; off <<= 1) {
        #pragma unroll
        for (int j = 0; j < 8; ++j) {
            ac0[j] += __shfl_xor(ac0[j], off);
            ac1[j] += __shfl_xor(ac1[j], off);
        }
    }

    if (kg == 0) {
        ushort8v h0, l0, h1, l1;
        #pragma unroll
        for (int j = 0; j < 8; ++j) {
            unsigned short hh0 = f2h(ac0[j]);
            h0[j] = hh0; l0[j] = f2h(ac0[j] - h2f(hh0));
            unsigned short hh1 = f2h(ac1[j]);
            h1[j] = hh1; l1[j] = f2h(ac1[j] - h2f(hh1));
        }
        size_t oi0 = ((size_t)b * S_ + s0) * DIM_ + h * HD_ + p8 * 8;
        size_t oi1 = oi0 + DIM_;
        *(ushort8v*)&Ohi[oi0] = h0;  *(ushort8v*)&Olo[oi0] = l0;
        *(ushort8v*)&Ohi[oi1] = h1;  *(ushort8v*)&Olo[oi1] = l1;
    }
}

// ---------------------------------------------------------------------------
// ws layout (bytes):
//   0    Q fp32 8MB | 8M K fp16 4MB | 16M V fp16 4MB
//   24M  x_hi/attn_hi fp16 4MB | 28M x_lo/attn_lo fp16 4MB
//   32M  Wqkv_h fp16 1.5M | +1.5M Wout_h fp16 0.5M
// ---------------------------------------------------------------------------
extern "C" void kernel_launch(void* const* d_in, const int* in_sizes, int n_in,
                              void* d_out, int out_size, void* d_ws, size_t ws_size,
                              hipStream_t stream)
{
    const float* x      = (const float*)d_in[0];
    const float* Wqkv   = (const float*)d_in[1];
    const float* bqkv   = (const float*)d_in[2];
    const float* Wout   = (const float*)d_in[3];
    const float* bout   = (const float*)d_in[4];
    const int*   routes = (const int*)d_in[5];
    float* out = (float*)d_out;

    char* w = (char*)d_ws;
    float*          Q  = (float*)(w);
    unsigned short* Kh = (unsigned short*)(w + (8u << 20));
    unsigned short* Vh = (unsigned short*)(w + (16u << 20));
    unsigned short* xh  = (unsigned short*)(w + (24u << 20));
    unsigned short* xl  = (unsigned short*)(w + (28u << 20));
    unsigned short* ah  = xh;   // aliased: free after qkv gemm
    unsigned short* al  = xl;
    unsigned short* wqh = (unsigned short*)(w + (32u << 20));
    unsigned short* woh = (unsigned short*)(w + (32u << 20) + 1572864u);

    dim3 blk(256);

    // fused prep: x-split (1024 blocks) + Wqkv transpose (768) + Wout (256)
    prep_all<<<dim3(2048), blk, 0, stream>>>(x, xh, xl, Wqkv, wqh, Wout, woh);

    // qkv: M=4096, N=1536, K=512 -> 16x32 = 512 blocks
    gemm_mfma<128, 96, 64, 48><<<dim3(NQKV_ / 96, M_ / 128), blk, 0, stream>>>(
        xh, xl, wqh, bqkv, nullptr, Q, Kh, Vh, NQKV_, DIM_, 1);

    attn_kernel<<<dim3((B_ * H_ * S_) / 8), blk, 0, stream>>>(Q, Kh, Vh, routes, ah, al);

    // out-proj: M=4096, N=512, K=512 -> 8x64 = 512 blocks
    gemm_mfma<64, 64, 32, 32><<<dim3(DIM_ / 64, M_ / 64), blk, 0, stream>>>(
        ah, al, woh, bout, out, nullptr, nullptr, nullptr, DIM_, DIM_, 0);
}

// Round 12
// 141.060 us; speedup vs baseline: 1.3602x; 1.0535x over previous
//
#include <hip/hip_runtime.h>
#include <math.h>

// CantorAttention: B=2, S=2048, DIM=512, H=8, HD=64, K=64
#define B_    2
#define S_    2048
#define DIM_  512
#define H_    8
#define HD_   64
#define K_    64
#define M_    (B_ * S_)          // 4096
#define NQKV_ (3 * DIM_)         // 1536

typedef __attribute__((ext_vector_type(8))) _Float16       half8;     // mfma A/B frag (8 f16)
typedef __attribute__((ext_vector_type(8))) unsigned short ushort8v;  // 16B move
typedef __attribute__((ext_vector_type(4))) float          float4v;   // mfma C/D frag

// ---- fp16 helpers ----------------------------------------------------------
__device__ __forceinline__ unsigned short f2h(float f) {
    _Float16 h = (_Float16)f;
    unsigned short u; __builtin_memcpy(&u, &h, 2); return u;
}
__device__ __forceinline__ float h2f(unsigned short u) {
    _Float16 h; __builtin_memcpy(&h, &u, 2); return (float)h;
}

// async 16B global -> LDS (lane l lands at ldsbase + l*16)
__device__ __forceinline__ void load_lds16(const unsigned short* g, unsigned short* l) {
    __builtin_amdgcn_global_load_lds(
        (const __attribute__((address_space(1))) void*)g,
        (__attribute__((address_space(3))) void*)l, 16, 0, 0);
}

// ---------------------------------------------------------------------------
// prep_all: one kernel, block-range partitioned.
//   [0,1024): split x fp32 -> xh/xl fp16 (8 elems/thread)
//   [1024,1792): transpose Wqkv -> Wqh fp16 [N][Kd] (48 x 16 tiles of 32x32)
//   [1792,2048): transpose Wout -> Woh fp16 (16 x 16 tiles)
// ---------------------------------------------------------------------------
__global__ __launch_bounds__(256) void prep_all(
    const float* __restrict__ X,
    unsigned short* __restrict__ Xhi, unsigned short* __restrict__ Xlo,
    const float* __restrict__ Wq, unsigned short* __restrict__ Wqh,
    const float* __restrict__ Wo, unsigned short* __restrict__ Woh)
{
    __shared__ float tile[32][33];
    const int bid = blockIdx.x, t = threadIdx.x;

    if (bid < 1024) {
        size_t i = ((size_t)bid * 256 + t) * 8;
        float4 a = *(const float4*)&X[i];
        float4 b = *(const float4*)&X[i + 4];
        float f[8] = {a.x, a.y, a.z, a.w, b.x, b.y, b.z, b.w};
        ushort8v h, l;
        #pragma unroll
        for (int j = 0; j < 8; ++j) {
            unsigned short hh = f2h(f[j]);
            h[j] = hh;
            l[j] = f2h(f[j] - h2f(hh));
        }
        *(ushort8v*)&Xhi[i] = h;
        *(ushort8v*)&Xlo[i] = l;
        return;
    }

    const float* W;
    unsigned short* Whi;
    int N, k0, n0;
    if (bid < 1792) {
        int idx = bid - 1024;                  // 768 blocks: 48 n-tiles x 16 k-tiles
        W = Wq; Whi = Wqh; N = NQKV_;
        n0 = (idx % 48) * 32; k0 = (idx / 48) * 32;
    } else {
        int idx = bid - 1792;                  // 256 blocks: 16 x 16
        W = Wo; Whi = Woh; N = DIM_;
        n0 = (idx % 16) * 32; k0 = (idx / 16) * 32;
    }
    const int c = t & 31, r8 = t >> 5;
    #pragma unroll
    for (int i = 0; i < 4; ++i) {
        int r = r8 + i * 8;
        tile[r][c] = W[(size_t)(k0 + r) * N + n0 + c];
    }
    __syncthreads();
    #pragma unroll
    for (int i = 0; i < 4; ++i) {
        int r = r8 + i * 8;                 // n offset
        Whi[(size_t)(n0 + r) * 512 + k0 + c] = f2h(tile[c][r]);   // Kd = 512
    }
}

// ---------------------------------------------------------------------------
// Split-fp16 MFMA GEMM. TERMS=2: C = (Ah+Al)*Wh (err ~2^-11). TERMS=1: C=Ah*Wh.
// Double-buffered global_load_lds staging (prefetch a compute phase ahead).
//   mode 0: row-major fp32 C.
//   mode 1: qkv scatter -> Q fp32 / K fp16 / V fp16, layout [B,H,S,HD].
// ---------------------------------------------------------------------------
template<int BM, int BN, int WM, int WN, int TERMS>
__global__ __launch_bounds__(256) void gemm_mfma(
    const unsigned short* __restrict__ Ahi, const unsigned short* __restrict__ Alo,
    const unsigned short* __restrict__ Wh,
    const float* __restrict__ bias, float* __restrict__ C,
    float* __restrict__ Qo, unsigned short* __restrict__ Kho, unsigned short* __restrict__ Vho,
    int N, int Kd, int mode)
{
    constexpr int TM = WM / 16, TN = WN / 16;
    constexpr int WAVES_N = BN / WN;
    __shared__ unsigned short Ah[2][BM][32];
    __shared__ unsigned short Al[TERMS == 2 ? 2 : 1][BM][32];
    __shared__ unsigned short Bh[2][BN][32];

    const int t = threadIdx.x, lane = t & 63, wave = t >> 6;
    const int wm = (wave / WAVES_N) * WM, wn = (wave % WAVES_N) * WN;
    const int m0 = blockIdx.y * BM, n0 = blockIdx.x * BN;
    const int l15 = lane & 15, l4 = lane >> 4;

    const int srow = lane >> 2;          // 0..15
    const int scol = (lane & 3) * 8;     // 0,8,16,24

    float4v acc[TM][TN];
    #pragma unroll
    for (int i = 0; i < TM; ++i)
        #pragma unroll
        for (int j = 0; j < TN; ++j)
            #pragma unroll
            for (int r = 0; r < 4; ++r) acc[i][j][r] = 0.f;

    const int NK = Kd / 32;

    #pragma unroll
    for (int c = wave; c < BM / 16; c += 4) {
        size_t g = (size_t)(m0 + c * 16 + srow) * Kd + scol;
        load_lds16(&Ahi[g], &Ah[0][c * 16][0]);
        if constexpr (TERMS == 2) load_lds16(&Alo[g], &Al[0][c * 16][0]);
    }
    #pragma unroll
    for (int c = wave; c < BN / 16; c += 4) {
        size_t g = (size_t)(n0 + c * 16 + srow) * Kd + scol;
        load_lds16(&Wh[g], &Bh[0][c * 16][0]);
    }
    __syncthreads();

    for (int ks = 0; ks < NK; ++ks) {
        const int cur = ks & 1, nxt = cur ^ 1;

        if (ks + 1 < NK) {
            const int k1 = (ks + 1) * 32;
            #pragma unroll
            for (int c = wave; c < BM / 16; c += 4) {
                size_t g = (size_t)(m0 + c * 16 + srow) * Kd + k1 + scol;
                load_lds16(&Ahi[g], &Ah[nxt][c * 16][0]);
                if constexpr (TERMS == 2) load_lds16(&Alo[g], &Al[nxt][c * 16][0]);
            }
            #pragma unroll
            for (int c = wave; c < BN / 16; c += 4) {
                size_t g = (size_t)(n0 + c * 16 + srow) * Kd + k1 + scol;
                load_lds16(&Wh[g], &Bh[nxt][c * 16][0]);
            }
        }

        half8 fa_h[TM], fa_l[TM], fb[TN];
        #pragma unroll
        for (int im = 0; im < TM; ++im) {
            fa_h[im] = *(const half8*)&Ah[cur][wm + im * 16 + l15][l4 * 8];
            if constexpr (TERMS == 2)
                fa_l[im] = *(const half8*)&Al[cur][wm + im * 16 + l15][l4 * 8];
        }
        #pragma unroll
        for (int in = 0; in < TN; ++in)
            fb[in] = *(const half8*)&Bh[cur][wn + in * 16 + l15][l4 * 8];
        #pragma unroll
        for (int im = 0; im < TM; ++im)
            #pragma unroll
            for (int in = 0; in < TN; ++in) {
                acc[im][in] = __builtin_amdgcn_mfma_f32_16x16x32_f16(fa_h[im], fb[in], acc[im][in], 0, 0, 0);
                if constexpr (TERMS == 2)
                    acc[im][in] = __builtin_amdgcn_mfma_f32_16x16x32_f16(fa_l[im], fb[in], acc[im][in], 0, 0, 0);
            }

        __syncthreads();
    }

    // epilogue: D row = (lane>>4)*4 + reg, col = lane&15  [m89-verified layout]
    if (mode == 0) {
        #pragma unroll
        for (int in = 0; in < TN; ++in) {
            int n = n0 + wn + in * 16 + l15;
            float bv = bias[n];
            #pragma unroll
            for (int im = 0; im < TM; ++im) {
                int mb = m0 + wm + im * 16 + l4 * 4;
                #pragma unroll
                for (int r = 0; r < 4; ++r)
                    C[(size_t)(mb + r) * N + n] = acc[im][in][r] + bv;
            }
        }
    } else {
        #pragma unroll
        for (int in = 0; in < TN; ++in) {
            int n = n0 + wn + in * 16 + l15;
            int which = n >> 9, h = (n >> 6) & 7, d = n & 63;
            float bv = bias[n];
            #pragma unroll
            for (int im = 0; im < TM; ++im) {
                int mb = m0 + wm + im * 16 + l4 * 4;
                #pragma unroll
                for (int r = 0; r < 4; ++r) {
                    int m = mb + r, b = m >> 11, s = m & 2047;
                    size_t idx = (((size_t)b * H_ + h) * S_ + s) * HD_ + d;
                    float val = acc[im][in][r] + bv;
                    if (which == 0)      Qo[idx]  = val;
                    else if (which == 1) Kho[idx] = f2h(val);
                    else                 Vho[idx] = f2h(val);
                }
            }
        }
    }
}

// ---------------------------------------------------------------------------
// Gathered attention: TWO queries per wave, XCD-pinned by (b,h). K/V fp16.
// Phase-2 V rows are PREFETCHED into registers before softmax (addresses
// depend only on routes), so the softmax shuffle chain hides the V-gather
// latency. Output single fp16 (feeds 1-term out-proj). 4096 blocks.
// ---------------------------------------------------------------------------
__global__ __launch_bounds__(256) void attn_kernel(
    const float* __restrict__ Q, const unsigned short* __restrict__ Kh,
    const unsigned short* __restrict__ Vh, const int* __restrict__ routes,
    unsigned short* __restrict__ Oh)
{
    __shared__ float q_s[4][2][64];
    __shared__ float w_s[4][2][64];

    const int wv = threadIdx.x >> 6, lane = threadIdx.x & 63;

    const int blk  = blockIdx.x;
    const int xcd  = blk & 7;
    const int idx  = blk >> 3;            // [0, 512)
    const int half = idx >> 8;            // 0 or 1
    const int sblk = idx & 255;           // [0, 256)
    const int bh   = xcd | (half << 3);   // [0, 16)
    const int s0   = sblk * 8 + wv * 2;   // this wave: s0, s0+1
    const int b    = bh >> 3, h = bh & 7;

    q_s[wv][0][lane] = Q[((size_t)bh * S_ + s0) * HD_ + lane];
    q_s[wv][1][lane] = Q[((size_t)bh * S_ + s0 + 1) * HD_ + lane];
    const int r0 = routes[s0 * K_ + lane];
    const int r1 = routes[(s0 + 1) * K_ + lane];
    __syncthreads();

    // phase 1: scores. 8 lanes per key (8 f16 = 16B per lane), 8 keys/pass.
    const int p = lane & 7, jl = lane >> 3;
    float qv0[8], qv1[8];
    #pragma unroll
    for (int i = 0; i < 8; ++i) {
        qv0[i] = q_s[wv][0][p * 8 + i];
        qv1[i] = q_s[wv][1][p * 8 + i];
    }

    const unsigned short* kbase = Kh + (size_t)bh * S_ * HD_;
    #pragma unroll
    for (int pass = 0; pass < 8; ++pass) {
        int j = pass * 8 + jl;
        int rj0 = __shfl(r0, j);
        int rj1 = __shfl(r1, j);
        ushort8v k0 = *(const ushort8v*)&kbase[(size_t)rj0 * HD_ + p * 8];
        ushort8v k1 = *(const ushort8v*)&kbase[(size_t)rj1 * HD_ + p * 8];
        float pa = 0.f, pb = 0.f;
        #pragma unroll
        for (int i = 0; i < 8; ++i) {
            pa += qv0[i] * h2f(k0[i]);
            pb += qv1[i] * h2f(k1[i]);
        }
        pa += __shfl_xor(pa, 1);  pb += __shfl_xor(pb, 1);
        pa += __shfl_xor(pa, 2);  pb += __shfl_xor(pb, 2);
        pa += __shfl_xor(pa, 4);  pb += __shfl_xor(pb, 4);
        if (p == 0) { w_s[wv][0][j] = pa * 0.125f; w_s[wv][1][j] = pb * 0.125f; }
    }
    __syncthreads();

    // prefetch ALL phase-2 V rows now (addresses known from routes) —
    // the loads' latency overlaps the softmax shuffle chain below.
    const int kg = lane >> 3, p8 = lane & 7;
    const unsigned short* vbase = Vh + (size_t)bh * S_ * HD_;
    ushort8v pv0[8], pv1[8];
    #pragma unroll
    for (int i = 0; i < 8; ++i) {
        int key = i * 8 + kg;
        int rj0 = __shfl(r0, key), rj1 = __shfl(r1, key);
        pv0[i] = *(const ushort8v*)&vbase[(size_t)rj0 * HD_ + p8 * 8];
        pv1[i] = *(const ushort8v*)&vbase[(size_t)rj1 * HD_ + p8 * 8];
    }

    // softmax (two independent shuffle chains) — overlaps V-load latency
    float sa = w_s[wv][0][lane], sb = w_s[wv][1][lane];
    float ma = sa, mb = sb;
    #pragma unroll
    for (int off = 32; off >= 1; off >>= 1) {
        ma = fmaxf(ma, __shfl_xor(ma, off));
        mb = fmaxf(mb, __shfl_xor(mb, off));
    }
    float ea = __expf(sa - ma), eb = __expf(sb - mb);
    float su_a = ea, su_b = eb;
    #pragma unroll
    for (int off = 32; off >= 1; off >>= 1) {
        su_a += __shfl_xor(su_a, off);
        su_b += __shfl_xor(su_b, off);
    }
    const float w0 = ea / su_a, w1 = eb / su_b;   // weight for key = lane

    // phase 2: FMA with prefetched V. lane = (key-group kg, d-slice p8).
    float ac0[8] = {0.f,0.f,0.f,0.f,0.f,0.f,0.f,0.f};
    float ac1[8] = {0.f,0.f,0.f,0.f,0.f,0.f,0.f,0.f};
    #pragma unroll
    for (int i = 0; i < 8; ++i) {
        int key = i * 8 + kg;
        float wj0 = __shfl(w0, key), wj1 = __shfl(w1, key);
        #pragma unroll
        for (int j = 0; j < 8; ++j) {
            ac0[j] += wj0 * h2f(pv0[i][j]);
            ac1[j] += wj1 * h2f(pv1[i][j]);
        }
    }
    // reduce across the 8 key-groups (lanes with same p8, kg varying)
    #pragma unroll
    for (int off = 8; off <= 32; off <<= 1) {
        #pragma unroll
        for (int j = 0; j < 8; ++j) {
            ac0[j] += __shfl_xor(ac0[j], off);
            ac1[j] += __shfl_xor(ac1[j], off);
        }
    }

    if (kg == 0) {
        ushort8v h0, h1;
        #pragma unroll
        for (int j = 0; j < 8; ++j) {
            h0[j] = f2h(ac0[j]);
            h1[j] = f2h(ac1[j]);
        }
        size_t oi0 = ((size_t)b * S_ + s0) * DIM_ + h * HD_ + p8 * 8;
        size_t oi1 = oi0 + DIM_;
        *(ushort8v*)&Oh[oi0] = h0;
        *(ushort8v*)&Oh[oi1] = h1;
    }
}

// ---------------------------------------------------------------------------
// ws layout (bytes):
//   0    Q fp32 8MB | 8M K fp16 4MB | 16M V fp16 4MB
//   24M  x_hi / attn fp16 4MB | 28M x_lo fp16 4MB
//   32M  Wqkv_h fp16 1.5M | +1.5M Wout_h fp16 0.5M
// ---------------------------------------------------------------------------
extern "C" void kernel_launch(void* const* d_in, const int* in_sizes, int n_in,
                              void* d_out, int out_size, void* d_ws, size_t ws_size,
                              hipStream_t stream)
{
    const float* x      = (const float*)d_in[0];
    const float* Wqkv   = (const float*)d_in[1];
    const float* bqkv   = (const float*)d_in[2];
    const float* Wout   = (const float*)d_in[3];
    const float* bout   = (const float*)d_in[4];
    const int*   routes = (const int*)d_in[5];
    float* out = (float*)d_out;

    char* w = (char*)d_ws;
    float*          Q  = (float*)(w);
    unsigned short* Kh = (unsigned short*)(w + (8u << 20));
    unsigned short* Vh = (unsigned short*)(w + (16u << 20));
    unsigned short* xh  = (unsigned short*)(w + (24u << 20));
    unsigned short* xl  = (unsigned short*)(w + (28u << 20));
    unsigned short* ah  = xh;   // aliased: free after qkv gemm
    unsigned short* wqh = (unsigned short*)(w + (32u << 20));
    unsigned short* woh = (unsigned short*)(w + (32u << 20) + 1572864u);

    dim3 blk(256);

    // fused prep: x-split (1024 blocks) + Wqkv transpose (768) + Wout (256)
    prep_all<<<dim3(2048), blk, 0, stream>>>(x, xh, xl, Wqkv, wqh, Wout, woh);

    // qkv: M=4096, N=1536, K=512 -> 16x32 = 512 blocks, 2-term A
    gemm_mfma<128, 96, 64, 48, 2><<<dim3(NQKV_ / 96, M_ / 128), blk, 0, stream>>>(
        xh, xl, wqh, bqkv, nullptr, Q, Kh, Vh, NQKV_, DIM_, 1);

    attn_kernel<<<dim3((B_ * H_ * S_) / 8), blk, 0, stream>>>(Q, Kh, Vh, routes, ah);

    // out-proj: M=4096, N=512, K=512 -> 8x64 = 512 blocks, 1-term A
    gemm_mfma<64, 64, 32, 32, 1><<<dim3(DIM_ / 64, M_ / 64), blk, 0, stream>>>(
        ah, nullptr, woh, bout, out, nullptr, nullptr, nullptr, DIM_, DIM_, 0);
}

// Round 13
// 132.549 us; speedup vs baseline: 1.4476x; 1.0642x over previous
//
#include <hip/hip_runtime.h>
#include <math.h>

// CantorAttention: B=2, S=2048, DIM=512, H=8, HD=64, K=64
#define B_    2
#define S_    2048
#define DIM_  512
#define H_    8
#define HD_   64
#define K_    64
#define M_    (B_ * S_)          // 4096
#define NQKV_ (3 * DIM_)         // 1536

typedef __attribute__((ext_vector_type(8))) _Float16       half8;     // mfma A/B frag (8 f16)
typedef __attribute__((ext_vector_type(2))) _Float16       half2v;    // fdot2 operand
typedef __attribute__((ext_vector_type(8))) unsigned short ushort8v;  // 16B move
typedef __attribute__((ext_vector_type(4))) float          float4v;   // mfma C/D frag

// ---- fp16 helpers ----------------------------------------------------------
__device__ __forceinline__ unsigned short f2h(float f) {
    _Float16 h = (_Float16)f;
    unsigned short u; __builtin_memcpy(&u, &h, 2); return u;
}
__device__ __forceinline__ float h2f(unsigned short u) {
    _Float16 h; __builtin_memcpy(&h, &u, 2); return (float)h;
}

// async 16B global -> LDS (lane l lands at ldsbase + l*16)
__device__ __forceinline__ void load_lds16(const unsigned short* g, unsigned short* l) {
    __builtin_amdgcn_global_load_lds(
        (const __attribute__((address_space(1))) void*)g,
        (__attribute__((address_space(3))) void*)l, 16, 0, 0);
}

// ---------------------------------------------------------------------------
// prep_all: one kernel, block-range partitioned.
//   [0,1024): convert x fp32 -> xh fp16 (8 elems/thread; 1-term scheme)
//   [1024,1792): transpose Wqkv -> Wqh fp16 [N][Kd] (48 x 16 tiles of 32x32)
//   [1792,2048): transpose Wout -> Woh fp16 (16 x 16 tiles)
// ---------------------------------------------------------------------------
__global__ __launch_bounds__(256) void prep_all(
    const float* __restrict__ X, unsigned short* __restrict__ Xh,
    const float* __restrict__ Wq, unsigned short* __restrict__ Wqh,
    const float* __restrict__ Wo, unsigned short* __restrict__ Woh)
{
    __shared__ float tile[32][33];
    const int bid = blockIdx.x, t = threadIdx.x;

    if (bid < 1024) {
        size_t i = ((size_t)bid * 256 + t) * 8;
        float4 a = *(const float4*)&X[i];
        float4 b = *(const float4*)&X[i + 4];
        float f[8] = {a.x, a.y, a.z, a.w, b.x, b.y, b.z, b.w};
        ushort8v h;
        #pragma unroll
        for (int j = 0; j < 8; ++j) h[j] = f2h(f[j]);
        *(ushort8v*)&Xh[i] = h;
        return;
    }

    const float* W;
    unsigned short* Whi;
    int N, k0, n0;
    if (bid < 1792) {
        int idx = bid - 1024;                  // 768 blocks: 48 n-tiles x 16 k-tiles
        W = Wq; Whi = Wqh; N = NQKV_;
        n0 = (idx % 48) * 32; k0 = (idx / 48) * 32;
    } else {
        int idx = bid - 1792;                  // 256 blocks: 16 x 16
        W = Wo; Whi = Woh; N = DIM_;
        n0 = (idx % 16) * 32; k0 = (idx / 16) * 32;
    }
    const int c = t & 31, r8 = t >> 5;
    #pragma unroll
    for (int i = 0; i < 4; ++i) {
        int r = r8 + i * 8;
        tile[r][c] = W[(size_t)(k0 + r) * N + n0 + c];
    }
    __syncthreads();
    #pragma unroll
    for (int i = 0; i < 4; ++i) {
        int r = r8 + i * 8;                 // n offset
        Whi[(size_t)(n0 + r) * 512 + k0 + c] = f2h(tile[c][r]);   // Kd = 512
    }
}

// ---------------------------------------------------------------------------
// fp16 MFMA GEMM. TERMS=2: C=(Ah+Al)*Wh. TERMS=1: C=Ah*Wh (err ~2^-10).
// Double-buffered global_load_lds staging (prefetch a compute phase ahead).
//   mode 0: row-major fp32 C.
//   mode 1: qkv scatter -> Q/K/V all fp16, layout [B,H,S,HD].
// ---------------------------------------------------------------------------
template<int BM, int BN, int WM, int WN, int TERMS>
__global__ __launch_bounds__(256) void gemm_mfma(
    const unsigned short* __restrict__ Ahi, const unsigned short* __restrict__ Alo,
    const unsigned short* __restrict__ Wh,
    const float* __restrict__ bias, float* __restrict__ C,
    unsigned short* __restrict__ Qho, unsigned short* __restrict__ Kho,
    unsigned short* __restrict__ Vho,
    int N, int Kd, int mode)
{
    constexpr int TM = WM / 16, TN = WN / 16;
    constexpr int WAVES_N = BN / WN;
    __shared__ unsigned short Ah[2][BM][32];
    __shared__ unsigned short Al[TERMS == 2 ? 2 : 1][TERMS == 2 ? BM : 1][32];
    __shared__ unsigned short Bh[2][BN][32];

    const int t = threadIdx.x, lane = t & 63, wave = t >> 6;
    const int wm = (wave / WAVES_N) * WM, wn = (wave % WAVES_N) * WN;
    const int m0 = blockIdx.y * BM, n0 = blockIdx.x * BN;
    const int l15 = lane & 15, l4 = lane >> 4;

    const int srow = lane >> 2;          // 0..15
    const int scol = (lane & 3) * 8;     // 0,8,16,24

    float4v acc[TM][TN];
    #pragma unroll
    for (int i = 0; i < TM; ++i)
        #pragma unroll
        for (int j = 0; j < TN; ++j)
            #pragma unroll
            for (int r = 0; r < 4; ++r) acc[i][j][r] = 0.f;

    const int NK = Kd / 32;

    #pragma unroll
    for (int c = wave; c < BM / 16; c += 4) {
        size_t g = (size_t)(m0 + c * 16 + srow) * Kd + scol;
        load_lds16(&Ahi[g], &Ah[0][c * 16][0]);
        if constexpr (TERMS == 2) load_lds16(&Alo[g], &Al[0][c * 16][0]);
    }
    #pragma unroll
    for (int c = wave; c < BN / 16; c += 4) {
        size_t g = (size_t)(n0 + c * 16 + srow) * Kd + scol;
        load_lds16(&Wh[g], &Bh[0][c * 16][0]);
    }
    __syncthreads();

    for (int ks = 0; ks < NK; ++ks) {
        const int cur = ks & 1, nxt = cur ^ 1;

        if (ks + 1 < NK) {
            const int k1 = (ks + 1) * 32;
            #pragma unroll
            for (int c = wave; c < BM / 16; c += 4) {
                size_t g = (size_t)(m0 + c * 16 + srow) * Kd + k1 + scol;
                load_lds16(&Ahi[g], &Ah[nxt][c * 16][0]);
                if constexpr (TERMS == 2) load_lds16(&Alo[g], &Al[nxt][c * 16][0]);
            }
            #pragma unroll
            for (int c = wave; c < BN / 16; c += 4) {
                size_t g = (size_t)(n0 + c * 16 + srow) * Kd + k1 + scol;
                load_lds16(&Wh[g], &Bh[nxt][c * 16][0]);
            }
        }

        half8 fa_h[TM], fa_l[TM], fb[TN];
        #pragma unroll
        for (int im = 0; im < TM; ++im) {
            fa_h[im] = *(const half8*)&Ah[cur][wm + im * 16 + l15][l4 * 8];
            if constexpr (TERMS == 2)
                fa_l[im] = *(const half8*)&Al[cur][wm + im * 16 + l15][l4 * 8];
        }
        #pragma unroll
        for (int in = 0; in < TN; ++in)
            fb[in] = *(const half8*)&Bh[cur][wn + in * 16 + l15][l4 * 8];
        #pragma unroll
        for (int im = 0; im < TM; ++im)
            #pragma unroll
            for (int in = 0; in < TN; ++in) {
                acc[im][in] = __builtin_amdgcn_mfma_f32_16x16x32_f16(fa_h[im], fb[in], acc[im][in], 0, 0, 0);
                if constexpr (TERMS == 2)
                    acc[im][in] = __builtin_amdgcn_mfma_f32_16x16x32_f16(fa_l[im], fb[in], acc[im][in], 0, 0, 0);
            }

        __syncthreads();
    }

    // epilogue: D row = (lane>>4)*4 + reg, col = lane&15  [m89-verified layout]
    if (mode == 0) {
        #pragma unroll
        for (int in = 0; in < TN; ++in) {
            int n = n0 + wn + in * 16 + l15;
            float bv = bias[n];
            #pragma unroll
            for (int im = 0; im < TM; ++im) {
                int mb = m0 + wm + im * 16 + l4 * 4;
                #pragma unroll
                for (int r = 0; r < 4; ++r)
                    C[(size_t)(mb + r) * N + n] = acc[im][in][r] + bv;
            }
        }
    } else {
        #pragma unroll
        for (int in = 0; in < TN; ++in) {
            int n = n0 + wn + in * 16 + l15;
            int which = n >> 9, h = (n >> 6) & 7, d = n & 63;
            unsigned short* dst = (which == 0) ? Qho : (which == 1 ? Kho : Vho);
            float bv = bias[n];
            #pragma unroll
            for (int im = 0; im < TM; ++im) {
                int mb = m0 + wm + im * 16 + l4 * 4;
                #pragma unroll
                for (int r = 0; r < 4; ++r) {
                    int m = mb + r, b = m >> 11, s = m & 2047;
                    dst[(((size_t)b * H_ + h) * S_ + s) * HD_ + d] =
                        f2h(acc[im][in][r] + bv);
                }
            }
        }
    }
}

// ---------------------------------------------------------------------------
// Gathered attention: TWO queries per wave, XCD-pinned by (b,h). Q/K/V fp16.
// Phase 1 uses v_dot2_f32_f16 (fdot2): 4 dot2 per 8-elem slice instead of
// 8 cvt + 8 fma. Phase-2 V rows prefetched into registers before softmax so
// the shuffle chain hides the gather latency. Output fp16. 4096 blocks.
// ---------------------------------------------------------------------------
__global__ __launch_bounds__(256) void attn_kernel(
    const unsigned short* __restrict__ Qh, const unsigned short* __restrict__ Kh,
    const unsigned short* __restrict__ Vh, const int* __restrict__ routes,
    unsigned short* __restrict__ Oh)
{
    __shared__ unsigned short q_s[4][2][64];
    __shared__ float w_s[4][2][64];

    const int wv = threadIdx.x >> 6, lane = threadIdx.x & 63;

    const int blk  = blockIdx.x;
    const int xcd  = blk & 7;
    const int idx  = blk >> 3;            // [0, 512)
    const int half = idx >> 8;            // 0 or 1
    const int sblk = idx & 255;           // [0, 256)
    const int bh   = xcd | (half << 3);   // [0, 16)
    const int s0   = sblk * 8 + wv * 2;   // this wave: s0, s0+1
    const int b    = bh >> 3, h = bh & 7;

    q_s[wv][0][lane] = Qh[((size_t)bh * S_ + s0) * HD_ + lane];
    q_s[wv][1][lane] = Qh[((size_t)bh * S_ + s0 + 1) * HD_ + lane];
    const int r0 = routes[s0 * K_ + lane];
    const int r1 = routes[(s0 + 1) * K_ + lane];
    __syncthreads();

    // phase 1: scores via fdot2. 8 lanes per key (8 f16 = 16B), 8 keys/pass.
    const int p = lane & 7, jl = lane >> 3;
    ushort8v qv0u = *(const ushort8v*)&q_s[wv][0][p * 8];
    ushort8v qv1u = *(const ushort8v*)&q_s[wv][1][p * 8];
    half2v qp0[4], qp1[4];
    __builtin_memcpy(qp0, &qv0u, 16);
    __builtin_memcpy(qp1, &qv1u, 16);

    const unsigned short* kbase = Kh + (size_t)bh * S_ * HD_;
    #pragma unroll
    for (int pass = 0; pass < 8; ++pass) {
        int j = pass * 8 + jl;
        int rj0 = __shfl(r0, j);
        int rj1 = __shfl(r1, j);
        ushort8v k0u = *(const ushort8v*)&kbase[(size_t)rj0 * HD_ + p * 8];
        ushort8v k1u = *(const ushort8v*)&kbase[(size_t)rj1 * HD_ + p * 8];
        half2v kp0[4], kp1[4];
        __builtin_memcpy(kp0, &k0u, 16);
        __builtin_memcpy(kp1, &k1u, 16);
        float pa = 0.f, pb = 0.f;
        #pragma unroll
        for (int i = 0; i < 4; ++i) {
            pa = __builtin_amdgcn_fdot2(qp0[i], kp0[i], pa, false);
            pb = __builtin_amdgcn_fdot2(qp1[i], kp1[i], pb, false);
        }
        pa += __shfl_xor(pa, 1);  pb += __shfl_xor(pb, 1);
        pa += __shfl_xor(pa, 2);  pb += __shfl_xor(pb, 2);
        pa += __shfl_xor(pa, 4);  pb += __shfl_xor(pb, 4);
        if (p == 0) { w_s[wv][0][j] = pa * 0.125f; w_s[wv][1][j] = pb * 0.125f; }
    }
    __syncthreads();

    // prefetch ALL phase-2 V rows (addresses depend only on routes) —
    // latency overlaps the softmax shuffle chain below.
    const int kg = lane >> 3, p8 = lane & 7;
    const unsigned short* vbase = Vh + (size_t)bh * S_ * HD_;
    ushort8v pv0[8], pv1[8];
    #pragma unroll
    for (int i = 0; i < 8; ++i) {
        int key = i * 8 + kg;
        int rj0 = __shfl(r0, key), rj1 = __shfl(r1, key);
        pv0[i] = *(const ushort8v*)&vbase[(size_t)rj0 * HD_ + p8 * 8];
        pv1[i] = *(const ushort8v*)&vbase[(size_t)rj1 * HD_ + p8 * 8];
    }

    // softmax (two independent shuffle chains)
    float sa = w_s[wv][0][lane], sb = w_s[wv][1][lane];
    float ma = sa, mb = sb;
    #pragma unroll
    for (int off = 32; off >= 1; off >>= 1) {
        ma = fmaxf(ma, __shfl_xor(ma, off));
        mb = fmaxf(mb, __shfl_xor(mb, off));
    }
    float ea = __expf(sa - ma), eb = __expf(sb - mb);
    float su_a = ea, su_b = eb;
    #pragma unroll
    for (int off = 32; off >= 1; off >>= 1) {
        su_a += __shfl_xor(su_a, off);
        su_b += __shfl_xor(su_b, off);
    }
    const float w0 = ea / su_a, w1 = eb / su_b;   // weight for key = lane

    // phase 2: FMA with prefetched V. lane = (key-group kg, d-slice p8).
    float ac0[8] = {0.f,0.f,0.f,0.f,0.f,0.f,0.f,0.f};
    float ac1[8] = {0.f,0.f,0.f,0.f,0.f,0.f,0.f,0.f};
    #pragma unroll
    for (int i = 0; i < 8; ++i) {
        int key = i * 8 + kg;
        float wj0 = __shfl(w0, key), wj1 = __shfl(w1, key);
        #pragma unroll
        for (int j = 0; j < 8; ++j) {
            ac0[j] += wj0 * h2f(pv0[i][j]);
            ac1[j] += wj1 * h2f(pv1[i][j]);
        }
    }
    // reduce across the 8 key-groups (lanes with same p8, kg varying)
    #pragma unroll
    for (int off = 8; off <= 32; off <<= 1) {
        #pragma unroll
        for (int j = 0; j < 8; ++j) {
            ac0[j] += __shfl_xor(ac0[j], off);
            ac1[j] += __shfl_xor(ac1[j], off);
        }
    }

    if (kg == 0) {
        ushort8v h0, h1;
        #pragma unroll
        for (int j = 0; j < 8; ++j) {
            h0[j] = f2h(ac0[j]);
            h1[j] = f2h(ac1[j]);
        }
        size_t oi0 = ((size_t)b * S_ + s0) * DIM_ + h * HD_ + p8 * 8;
        size_t oi1 = oi0 + DIM_;
        *(ushort8v*)&Oh[oi0] = h0;
        *(ushort8v*)&Oh[oi1] = h1;
    }
}

// ---------------------------------------------------------------------------
// ws layout (bytes):
//   0    Q fp16 4MB | 8M K fp16 4MB | 16M V fp16 4MB
//   24M  x_h / attn fp16 4MB
//   32M  Wqkv_h fp16 1.5M | +1.5M Wout_h fp16 0.5M
// ---------------------------------------------------------------------------
extern "C" void kernel_launch(void* const* d_in, const int* in_sizes, int n_in,
                              void* d_out, int out_size, void* d_ws, size_t ws_size,
                              hipStream_t stream)
{
    const float* x      = (const float*)d_in[0];
    const float* Wqkv   = (const float*)d_in[1];
    const float* bqkv   = (const float*)d_in[2];
    const float* Wout   = (const float*)d_in[3];
    const float* bout   = (const float*)d_in[4];
    const int*   routes = (const int*)d_in[5];
    float* out = (float*)d_out;

    char* w = (char*)d_ws;
    unsigned short* Qh = (unsigned short*)(w);
    unsigned short* Kh = (unsigned short*)(w + (8u << 20));
    unsigned short* Vh = (unsigned short*)(w + (16u << 20));
    unsigned short* xh = (unsigned short*)(w + (24u << 20));
    unsigned short* ah = xh;   // aliased: free after qkv gemm
    unsigned short* wqh = (unsigned short*)(w + (32u << 20));
    unsigned short* woh = (unsigned short*)(w + (32u << 20) + 1572864u);

    dim3 blk(256);

    // fused prep: x-convert (1024 blocks) + Wqkv transpose (768) + Wout (256)
    prep_all<<<dim3(2048), blk, 0, stream>>>(x, xh, Wqkv, wqh, Wout, woh);

    // qkv: M=4096, N=1536, K=512 -> 16x32 = 512 blocks, 1-term A
    gemm_mfma<128, 96, 64, 48, 1><<<dim3(NQKV_ / 96, M_ / 128), blk, 0, stream>>>(
        xh, nullptr, wqh, bqkv, nullptr, Qh, Kh, Vh, NQKV_, DIM_, 1);

    attn_kernel<<<dim3((B_ * H_ * S_) / 8), blk, 0, stream>>>(Qh, Kh, Vh, routes, ah);

    // out-proj: M=4096, N=512, K=512 -> 8x64 = 512 blocks, 1-term A
    gemm_mfma<64, 64, 32, 32, 1><<<dim3(DIM_ / 64, M_ / 64), blk, 0, stream>>>(
        ah, nullptr, woh, bout, out, nullptr, nullptr, nullptr, DIM_, DIM_, 0);
}